// Round 1
// baseline (1054.898 us; speedup 1.0000x reference)
//
#include <hip/hip_runtime.h>
#include <hip/hip_bf16.h>
#include <math.h>

#define N_NODES 50000
#define N_EDGES 800000
#define F_IN 128

__device__ __forceinline__ float elu_f(float x)   { return x > 0.f ? x : expm1f(x); }
__device__ __forceinline__ float lrelu_f(float x) { return x > 0.f ? x : 0.2f * x; }
__device__ __forceinline__ int   clampN(int v)    { return v < 0 ? 0 : (v >= N_NODES ? N_NODES - 1 : v); }

// ---------------- CSR build ----------------
__global__ void k_count(const int* __restrict__ dst, int* __restrict__ counts) {
    int e = blockIdx.x * blockDim.x + threadIdx.x;
    if (e < N_EDGES) atomicAdd(&counts[clampN(dst[e])], 1);
}

// single-block exclusive scan of counts[N] -> offsets[N+1], cursor copy
__global__ void k_scan(const int* __restrict__ counts, int* __restrict__ offsets,
                       int* __restrict__ cursor) {
    __shared__ int wsum[16];
    __shared__ int wbase[16];
    __shared__ int s_base;
    int tid = threadIdx.x;            // 0..1023
    int lane = tid & 63, wid = tid >> 6;
    if (tid == 0) s_base = 0;
    __syncthreads();
    for (int start = 0; start < N_NODES; start += 1024) {
        int i = start + tid;
        int v = (i < N_NODES) ? counts[i] : 0;
        int x = v;
        #pragma unroll
        for (int d = 1; d < 64; d <<= 1) {
            int t = __shfl_up(x, d, 64);
            if (lane >= d) x += t;
        }
        if (lane == 63) wsum[wid] = x;
        __syncthreads();
        if (tid == 0) {
            int b = s_base;
            for (int w = 0; w < 16; ++w) { wbase[w] = b; b += wsum[w]; }
            s_base = b;
        }
        __syncthreads();
        if (i < N_NODES) {
            int excl = wbase[wid] + x - v;
            offsets[i] = excl;
            cursor[i]  = excl;
        }
        __syncthreads();
    }
    if (tid == 0) offsets[N_NODES] = s_base;
}

__global__ void k_scatter(const int* __restrict__ src, const int* __restrict__ dst,
                          int* __restrict__ cursor, int* __restrict__ csr) {
    int e = blockIdx.x * blockDim.x + threadIdx.x;
    if (e < N_EDGES) {
        int d = clampN(dst[e]);
        int pos = atomicAdd(&cursor[d], 1);
        csr[pos] = clampN(src[e]);
    }
}

// ---------------- GraphConv ----------------
// nbr[i] = sum_{e: dst==i} x[src[e]]
__global__ void k_gather(const float* __restrict__ x, const int* __restrict__ offsets,
                         const int* __restrict__ csr, float* __restrict__ nbr) {
    int i = blockIdx.x;
    int c = threadIdx.x;                 // 0..127
    int k0 = offsets[i], k1 = offsets[i + 1];
    float acc = 0.f;
    for (int k = k0; k < k1; ++k) {
        int s = csr[k];
        acc += x[(size_t)s * F_IN + c];
    }
    nbr[(size_t)i * F_IN + c] = acc;
}

// h = elu(nbr @ W_rel^T + b_rel + x @ W_root^T), 8 nodes / block
__global__ void k_linear1(const float* __restrict__ x, const float* __restrict__ nbr,
                          const float* __restrict__ W_rel, const float* __restrict__ b_rel,
                          const float* __restrict__ W_root, float* __restrict__ h) {
    __shared__ float sN[8][128];
    __shared__ float sX[8][128];
    int tid = threadIdx.x;
    int node0 = blockIdx.x * 8;
    for (int j = tid; j < 8 * 128; j += 256) {
        int n = j >> 7, c = j & 127;
        int gi = node0 + n;
        float vn = 0.f, vx = 0.f;
        if (gi < N_NODES) { vn = nbr[(size_t)gi * 128 + c]; vx = x[(size_t)gi * 128 + c]; }
        sN[n][c] = vn; sX[n][c] = vx;
    }
    __syncthreads();
    int c = tid & 127;
    int g = tid >> 7;    // 0..1
    float a0 = 0.f, a1 = 0.f, a2 = 0.f, a3 = 0.f;
    for (int k = 0; k < 128; ++k) {
        float wr = W_rel[c * 128 + k];
        float wo = W_root[c * 128 + k];
        a0 += sN[g + 0][k] * wr + sX[g + 0][k] * wo;
        a1 += sN[g + 2][k] * wr + sX[g + 2][k] * wo;
        a2 += sN[g + 4][k] * wr + sX[g + 4][k] * wo;
        a3 += sN[g + 6][k] * wr + sX[g + 6][k] * wo;
    }
    float b = b_rel[c];
    int i0 = node0 + g;
    if (i0 + 0 < N_NODES) h[(size_t)(i0 + 0) * 128 + c] = elu_f(a0 + b);
    if (i0 + 2 < N_NODES) h[(size_t)(i0 + 2) * 128 + c] = elu_f(a1 + b);
    if (i0 + 4 < N_NODES) h[(size_t)(i0 + 4) * 128 + c] = elu_f(a2 + b);
    if (i0 + 6 < N_NODES) h[(size_t)(i0 + 6) * 128 + c] = elu_f(a3 + b);
}

// ---------------- GAT layer 1 (8 heads x 8 ch) ----------------
// z1 = h @ W1^T ; as1/ad1 per (node, head)
__global__ void k_gat1pre(const float* __restrict__ h, const float* __restrict__ W1,
                          const float* __restrict__ a_src, const float* __restrict__ a_dst,
                          float* __restrict__ z1, float* __restrict__ as1, float* __restrict__ ad1) {
    __shared__ float sH[4][128];
    int tid = threadIdx.x;
    int node0 = blockIdx.x * 4;
    for (int j = tid; j < 4 * 128; j += 256) {
        int n = j >> 7, c = j & 127;
        int gi = node0 + n;
        sH[n][c] = (gi < N_NODES) ? h[(size_t)gi * 128 + c] : 0.f;
    }
    __syncthreads();
    int c = tid & 63;
    int g = tid >> 6;     // 0..3, one wave per node
    float acc = 0.f;
    for (int k = 0; k < 128; ++k) acc += sH[g][k] * W1[c * 128 + k];
    int i = node0 + g;
    if (i < N_NODES) z1[(size_t)i * 64 + c] = acc;
    float ps = acc * a_src[c];
    float pd = acc * a_dst[c];
    #pragma unroll
    for (int d = 4; d >= 1; d >>= 1) {
        ps += __shfl_down(ps, d, 8);
        pd += __shfl_down(pd, d, 8);
    }
    if ((c & 7) == 0 && i < N_NODES) {
        as1[(size_t)i * 8 + (c >> 3)] = ps;
        ad1[(size_t)i * 8 + (c >> 3)] = pd;
    }
}

// per-dst softmax + aggregation; 1 wave per node; self-loop included
__global__ void k_gat1attn(const float* __restrict__ z1, const float* __restrict__ as1,
                           const float* __restrict__ ad1, const float* __restrict__ b1,
                           const int* __restrict__ offsets, const int* __restrict__ csr,
                           float* __restrict__ h2) {
    int i = blockIdx.x;
    int t = threadIdx.x;     // 0..63
    int hd = t >> 3;
    int k0 = offsets[i], k1 = offsets[i + 1];
    float ad = ad1[(size_t)i * 8 + hd];
    float self_l = lrelu_f(as1[(size_t)i * 8 + hd] + ad);

    // pass 1 (lanes 0..7, lane = head): running max incl. self-loop
    float m = 0.f, den = 0.f;
    if (t < 8) {
        float adh = ad1[(size_t)i * 8 + t];
        m = lrelu_f(as1[(size_t)i * 8 + t] + adh);
        for (int k = k0; k < k1; ++k) {
            int s = csr[k];
            m = fmaxf(m, lrelu_f(as1[(size_t)s * 8 + t] + adh));
        }
        // pass 2: denom
        den = expf(lrelu_f(as1[(size_t)i * 8 + t] + adh) - m);
        for (int k = k0; k < k1; ++k) {
            int s = csr[k];
            den += expf(lrelu_f(as1[(size_t)s * 8 + t] + adh) - m);
        }
    }
    float mh  = __shfl(m, hd, 64);
    float inv = 1.f / (__shfl(den, hd, 64) + 1e-16f);

    // pass 3: weighted aggregation (all 64 lanes, lane = out channel)
    float acc = expf(self_l - mh) * inv * z1[(size_t)i * 64 + t];
    for (int k = k0; k < k1; ++k) {
        int s = csr[k];
        float w = expf(lrelu_f(as1[(size_t)s * 8 + hd] + ad) - mh) * inv;
        acc += w * z1[(size_t)s * 64 + t];
    }
    h2[(size_t)i * 64 + t] = elu_f(acc + b1[t]);
}

// ---------------- GAT layer 2 (1 head x 64 ch) ----------------
__global__ void k_gat2pre(const float* __restrict__ h2, const float* __restrict__ W2,
                          const float* __restrict__ a_src, const float* __restrict__ a_dst,
                          float* __restrict__ z2, float* __restrict__ as2, float* __restrict__ ad2) {
    __shared__ float sH[4][64];
    int tid = threadIdx.x;
    int node0 = blockIdx.x * 4;
    for (int j = tid; j < 4 * 64; j += 256) {
        int n = j >> 6, c = j & 63;
        int gi = node0 + n;
        sH[n][c] = (gi < N_NODES) ? h2[(size_t)gi * 64 + c] : 0.f;
    }
    __syncthreads();
    int c = tid & 63;
    int g = tid >> 6;
    float acc = 0.f;
    for (int k = 0; k < 64; ++k) acc += sH[g][k] * W2[c * 64 + k];
    int i = node0 + g;
    if (i < N_NODES) z2[(size_t)i * 64 + c] = acc;
    float ps = acc * a_src[c];
    float pd = acc * a_dst[c];
    #pragma unroll
    for (int d = 32; d >= 1; d >>= 1) {
        ps += __shfl_down(ps, d, 64);
        pd += __shfl_down(pd, d, 64);
    }
    if (c == 0 && i < N_NODES) { as2[i] = ps; ad2[i] = pd; }
}

__global__ void k_gat2attn(const float* __restrict__ z2, const float* __restrict__ as2,
                           const float* __restrict__ ad2, const float* __restrict__ b2,
                           const int* __restrict__ offsets, const int* __restrict__ csr,
                           float* __restrict__ h3) {
    int i = blockIdx.x;
    int t = threadIdx.x;     // 0..63
    int k0 = offsets[i], k1 = offsets[i + 1];
    float ad = ad2[i];
    float self_l = lrelu_f(as2[i] + ad);
    // pass 1: max (edges distributed over lanes, lane0 adds self)
    float m = (t == 0) ? self_l : -1e30f;
    for (int k = k0 + t; k < k1; k += 64) m = fmaxf(m, lrelu_f(as2[csr[k]] + ad));
    #pragma unroll
    for (int d = 32; d >= 1; d >>= 1) m = fmaxf(m, __shfl_xor(m, d, 64));
    // pass 2: denom
    float ds = (t == 0) ? expf(self_l - m) : 0.f;
    for (int k = k0 + t; k < k1; k += 64) ds += expf(lrelu_f(as2[csr[k]] + ad) - m);
    #pragma unroll
    for (int d = 32; d >= 1; d >>= 1) ds += __shfl_xor(ds, d, 64);
    float inv = 1.f / (ds + 1e-16f);
    // pass 3: aggregation
    float acc = expf(self_l - m) * inv * z2[(size_t)i * 64 + t];
    for (int k = k0; k < k1; ++k) {
        int s = csr[k];
        float w = expf(lrelu_f(as2[s] + ad) - m) * inv;
        acc += w * z2[(size_t)s * 64 + t];
    }
    h3[(size_t)i * 64 + t] = acc + b2[t];
}

// ---------------- final mean + linear ----------------
__global__ void k_reduce(const float* __restrict__ h3, const float* __restrict__ Wr,
                         float* __restrict__ red) {
    __shared__ float lds[4];
    int tid = threadIdx.x;
    long long idx = (long long)blockIdx.x * blockDim.x + tid;
    long long total = (long long)N_NODES * 64;
    long long stride = (long long)gridDim.x * blockDim.x;
    float acc = 0.f;
    for (long long p = idx; p < total; p += stride)
        acc += h3[p] * Wr[p & 63];
    #pragma unroll
    for (int d = 32; d >= 1; d >>= 1) acc += __shfl_down(acc, d, 64);
    if ((tid & 63) == 0) lds[tid >> 6] = acc;
    __syncthreads();
    if (tid == 0) {
        float s = lds[0] + lds[1] + lds[2] + lds[3];
        atomicAdd(red, s);
    }
}

__global__ void k_finalize(const float* __restrict__ red, const float* __restrict__ br,
                           float* __restrict__ out) {
    out[0] = red[0] * (1.0f / N_NODES) + br[0];
}

extern "C" void kernel_launch(void* const* d_in, const int* in_sizes, int n_in,
                              void* d_out, int out_size, void* d_ws, size_t ws_size,
                              hipStream_t stream) {
    const float* x      = (const float*)d_in[0];
    const int*   edges  = (const int*)d_in[1];
    const float* W_rel  = (const float*)d_in[2];
    const float* b_rel  = (const float*)d_in[3];
    const float* W_root = (const float*)d_in[4];
    const float* W1     = (const float*)d_in[5];
    const float* a1s    = (const float*)d_in[6];
    const float* a1d    = (const float*)d_in[7];
    const float* b1     = (const float*)d_in[8];
    const float* W2     = (const float*)d_in[9];
    const float* a2s    = (const float*)d_in[10];
    const float* a2d    = (const float*)d_in[11];
    const float* b2     = (const float*)d_in[12];
    const float* Wr     = (const float*)d_in[13];
    const float* br     = (const float*)d_in[14];
    float* out = (float*)d_out;

    const int* src = edges;
    const int* dst = edges + N_EDGES;

    char* ws = (char*)d_ws;
    size_t p = 0;
    auto alloc = [&](size_t bytes) -> void* {
        void* r = ws + p;
        p = (p + bytes + 255) & ~(size_t)255;
        return r;
    };
    int*   counts  = (int*)alloc((size_t)N_NODES * 4);
    int*   offsets = (int*)alloc((size_t)(N_NODES + 1) * 4);
    int*   cursor  = (int*)alloc((size_t)N_NODES * 4);
    int*   csr     = (int*)alloc((size_t)N_EDGES * 4);
    float* nbr     = (float*)alloc((size_t)N_NODES * 128 * 4);
    float* h       = (float*)alloc((size_t)N_NODES * 128 * 4);
    float* z1      = (float*)alloc((size_t)N_NODES * 64 * 4);
    float* as1     = (float*)alloc((size_t)N_NODES * 8 * 4);
    float* ad1     = (float*)alloc((size_t)N_NODES * 8 * 4);
    float* h2      = (float*)alloc((size_t)N_NODES * 64 * 4);
    float* z2      = (float*)alloc((size_t)N_NODES * 64 * 4);
    float* as2     = (float*)alloc((size_t)N_NODES * 4);
    float* ad2     = (float*)alloc((size_t)N_NODES * 4);
    float* red     = (float*)alloc(4);
    float* h3      = nbr;   // reuse: nbr dead after k_linear1

    hipMemsetAsync(counts, 0, (size_t)N_NODES * 4, stream);
    hipMemsetAsync(red, 0, 4, stream);

    k_count   <<<(N_EDGES + 255) / 256, 256, 0, stream>>>(dst, counts);
    k_scan    <<<1, 1024, 0, stream>>>(counts, offsets, cursor);
    k_scatter <<<(N_EDGES + 255) / 256, 256, 0, stream>>>(src, dst, cursor, csr);
    k_gather  <<<N_NODES, 128, 0, stream>>>(x, offsets, csr, nbr);
    k_linear1 <<<(N_NODES + 7) / 8, 256, 0, stream>>>(x, nbr, W_rel, b_rel, W_root, h);
    k_gat1pre <<<(N_NODES + 3) / 4, 256, 0, stream>>>(h, W1, a1s, a1d, z1, as1, ad1);
    k_gat1attn<<<N_NODES, 64, 0, stream>>>(z1, as1, ad1, b1, offsets, csr, h2);
    k_gat2pre <<<(N_NODES + 3) / 4, 256, 0, stream>>>(h2, W2, a2s, a2d, z2, as2, ad2);
    k_gat2attn<<<N_NODES, 64, 0, stream>>>(z2, as2, ad2, b2, offsets, csr, h3);
    k_reduce  <<<256, 256, 0, stream>>>(h3, Wr, red);
    k_finalize<<<1, 1, 0, stream>>>(red, br, out);
}

// Round 2
// 737.046 us; speedup vs baseline: 1.4313x; 1.4313x over previous
//
#include <hip/hip_runtime.h>
#include <hip/hip_bf16.h>
#include <math.h>

#define N_NODES 50000
#define N_EDGES 800000
#define F_IN 128

__device__ __forceinline__ float elu_f(float x)   { return x > 0.f ? x : expm1f(x); }
__device__ __forceinline__ float lrelu_f(float x) { return x > 0.f ? x : 0.2f * x; }
__device__ __forceinline__ int   clampN(int v)    { return v < 0 ? 0 : (v >= N_NODES ? N_NODES - 1 : v); }

// ---------------- CSR build ----------------
__global__ void k_count(const int* __restrict__ dst, int* __restrict__ counts) {
    int e = blockIdx.x * blockDim.x + threadIdx.x;
    if (e < N_EDGES) atomicAdd(&counts[clampN(dst[e])], 1);
}

__global__ void k_scan(const int* __restrict__ counts, int* __restrict__ offsets,
                       int* __restrict__ cursor) {
    __shared__ int wsum[16];
    __shared__ int wbase[16];
    __shared__ int s_base;
    int tid = threadIdx.x;
    int lane = tid & 63, wid = tid >> 6;
    if (tid == 0) s_base = 0;
    __syncthreads();
    for (int start = 0; start < N_NODES; start += 1024) {
        int i = start + tid;
        int v = (i < N_NODES) ? counts[i] : 0;
        int x = v;
        #pragma unroll
        for (int d = 1; d < 64; d <<= 1) {
            int t = __shfl_up(x, d, 64);
            if (lane >= d) x += t;
        }
        if (lane == 63) wsum[wid] = x;
        __syncthreads();
        if (tid == 0) {
            int b = s_base;
            for (int w = 0; w < 16; ++w) { wbase[w] = b; b += wsum[w]; }
            s_base = b;
        }
        __syncthreads();
        if (i < N_NODES) {
            int excl = wbase[wid] + x - v;
            offsets[i] = excl;
            cursor[i]  = excl;
        }
        __syncthreads();
    }
    if (tid == 0) offsets[N_NODES] = s_base;
}

__global__ void k_scatter(const int* __restrict__ src, const int* __restrict__ dst,
                          int* __restrict__ cursor, int* __restrict__ csr) {
    int e = blockIdx.x * blockDim.x + threadIdx.x;
    if (e < N_EDGES) {
        int d = clampN(dst[e]);
        int pos = atomicAdd(&cursor[d], 1);
        csr[pos] = clampN(src[e]);
    }
}

// ---------------- GraphConv gather ----------------
__global__ void k_gather(const float* __restrict__ x, const int* __restrict__ offsets,
                         const int* __restrict__ csr, float* __restrict__ nbr) {
    int i = blockIdx.x;
    int c = threadIdx.x;                 // 0..127
    int k0 = offsets[i], k1 = offsets[i + 1];
    float acc = 0.f;
    for (int k = k0; k < k1; ++k) {
        int s = csr[k];
        acc += x[(size_t)s * F_IN + c];
    }
    nbr[(size_t)i * F_IN + c] = acc;
}

// ---------------- tiled GEMM: h = elu(nbr@W_rel^T + b_rel + x@W_root^T) ----------------
// BM=64 nodes, BN=128 (all outputs), BK=16. 256 threads: each does 4m x 8n.
__global__ __launch_bounds__(256) void k_linear1(
        const float* __restrict__ x, const float* __restrict__ nbr,
        const float* __restrict__ W_rel, const float* __restrict__ b_rel,
        const float* __restrict__ W_root, float* __restrict__ h) {
    __shared__ __align__(16) float sX[16][68];
    __shared__ __align__(16) float sN[16][68];
    __shared__ __align__(16) float sWr[16][132];
    __shared__ __align__(16) float sWo[16][132];
    int tid = threadIdx.x;
    int node0 = blockIdx.x * 64;
    int tx = tid & 15, ty = tid >> 4;
    int c0 = tx * 8, m0 = ty * 4;
    float acc[4][8] = {};
    int kk = tid & 15;      // k within tile
    int rb = tid >> 4;      // 0..15
    for (int k0 = 0; k0 < 128; k0 += 16) {
        #pragma unroll
        for (int r = 0; r < 4; ++r) {
            int m = rb + 16 * r;
            int gi = node0 + m; if (gi >= N_NODES) gi = N_NODES - 1;
            sX[kk][m] = x[(size_t)gi * 128 + k0 + kk];
            sN[kk][m] = nbr[(size_t)gi * 128 + k0 + kk];
        }
        #pragma unroll
        for (int r = 0; r < 8; ++r) {
            int c = rb + 16 * r;
            sWr[kk][c] = W_rel[c * 128 + k0 + kk];
            sWo[kk][c] = W_root[c * 128 + k0 + kk];
        }
        __syncthreads();
        #pragma unroll
        for (int k = 0; k < 16; ++k) {
            float4 ax = *(const float4*)&sX[k][m0];
            float4 an = *(const float4*)&sN[k][m0];
            float4 wr0 = *(const float4*)&sWr[k][c0];
            float4 wr1 = *(const float4*)&sWr[k][c0 + 4];
            float4 wo0 = *(const float4*)&sWo[k][c0];
            float4 wo1 = *(const float4*)&sWo[k][c0 + 4];
            float am[4] = {ax.x, ax.y, ax.z, ax.w};
            float nm[4] = {an.x, an.y, an.z, an.w};
            float wr[8] = {wr0.x, wr0.y, wr0.z, wr0.w, wr1.x, wr1.y, wr1.z, wr1.w};
            float wo[8] = {wo0.x, wo0.y, wo0.z, wo0.w, wo1.x, wo1.y, wo1.z, wo1.w};
            #pragma unroll
            for (int i = 0; i < 4; ++i)
                #pragma unroll
                for (int j = 0; j < 8; ++j)
                    acc[i][j] += nm[i] * wr[j] + am[i] * wo[j];
        }
        __syncthreads();
    }
    #pragma unroll
    for (int i = 0; i < 4; ++i) {
        int gi = node0 + m0 + i;
        if (gi < N_NODES) {
            #pragma unroll
            for (int j = 0; j < 8; ++j) {
                float v = elu_f(acc[i][j] + b_rel[c0 + j]);
                h[(size_t)gi * 128 + c0 + j] = v;
            }
        }
    }
}

// ---------------- tiled GEMM: Z[N x 64] = A[N x K] @ W[64 x K]^T ----------------
// BM=64, BN=64, BK=16. 256 threads: each does 4m x 4n.
template<int K>
__global__ __launch_bounds__(256) void k_gemm64(
        const float* __restrict__ A, const float* __restrict__ W,
        float* __restrict__ Z) {
    __shared__ __align__(16) float sA[16][68];
    __shared__ __align__(16) float sW[16][68];
    int tid = threadIdx.x;
    int node0 = blockIdx.x * 64;
    int tx = tid & 15, ty = tid >> 4;
    int c0 = tx * 4, m0 = ty * 4;
    float acc[4][4] = {};
    int kk = tid & 15;
    int rb = tid >> 4;
    for (int k0 = 0; k0 < K; k0 += 16) {
        #pragma unroll
        for (int r = 0; r < 4; ++r) {
            int m = rb + 16 * r;
            int gi = node0 + m; if (gi >= N_NODES) gi = N_NODES - 1;
            sA[kk][m] = A[(size_t)gi * K + k0 + kk];
            sW[kk][m] = W[m * K + k0 + kk];   // m doubles as c index 0..63
        }
        __syncthreads();
        #pragma unroll
        for (int k = 0; k < 16; ++k) {
            float4 av = *(const float4*)&sA[k][m0];
            float4 wv = *(const float4*)&sW[k][c0];
            float am[4] = {av.x, av.y, av.z, av.w};
            float wc[4] = {wv.x, wv.y, wv.z, wv.w};
            #pragma unroll
            for (int i = 0; i < 4; ++i)
                #pragma unroll
                for (int j = 0; j < 4; ++j)
                    acc[i][j] += am[i] * wc[j];
        }
        __syncthreads();
    }
    #pragma unroll
    for (int i = 0; i < 4; ++i) {
        int gi = node0 + m0 + i;
        if (gi < N_NODES) {
            float4 o = make_float4(acc[i][0], acc[i][1], acc[i][2], acc[i][3]);
            *(float4*)&Z[(size_t)gi * 64 + c0] = o;
        }
    }
}

// ---------------- alpha scalars ----------------
// GAT1: 8 heads x 8 ch; one wave per node, lane = channel
__global__ void k_alpha1(const float* __restrict__ z1, const float* __restrict__ a_src,
                         const float* __restrict__ a_dst,
                         float* __restrict__ as1, float* __restrict__ ad1) {
    int i = blockIdx.x * 4 + (threadIdx.x >> 6);
    int c = threadIdx.x & 63;
    if (i >= N_NODES) return;
    float v = z1[(size_t)i * 64 + c];
    float ps = v * a_src[c];
    float pd = v * a_dst[c];
    #pragma unroll
    for (int d = 4; d >= 1; d >>= 1) {
        ps += __shfl_down(ps, d, 8);
        pd += __shfl_down(pd, d, 8);
    }
    if ((c & 7) == 0) {
        as1[(size_t)i * 8 + (c >> 3)] = ps;
        ad1[(size_t)i * 8 + (c >> 3)] = pd;
    }
}

// GAT2: 1 head x 64 ch
__global__ void k_alpha2(const float* __restrict__ z2, const float* __restrict__ a_src,
                         const float* __restrict__ a_dst,
                         float* __restrict__ as2, float* __restrict__ ad2) {
    int i = blockIdx.x * 4 + (threadIdx.x >> 6);
    int c = threadIdx.x & 63;
    if (i >= N_NODES) return;
    float v = z2[(size_t)i * 64 + c];
    float ps = v * a_src[c];
    float pd = v * a_dst[c];
    #pragma unroll
    for (int d = 32; d >= 1; d >>= 1) {
        ps += __shfl_down(ps, d, 64);
        pd += __shfl_down(pd, d, 64);
    }
    if (c == 0) { as2[i] = ps; ad2[i] = pd; }
}

// ---------------- GAT attention (unchanged) ----------------
__global__ void k_gat1attn(const float* __restrict__ z1, const float* __restrict__ as1,
                           const float* __restrict__ ad1, const float* __restrict__ b1,
                           const int* __restrict__ offsets, const int* __restrict__ csr,
                           float* __restrict__ h2) {
    int i = blockIdx.x;
    int t = threadIdx.x;     // 0..63
    int hd = t >> 3;
    int k0 = offsets[i], k1 = offsets[i + 1];
    float ad = ad1[(size_t)i * 8 + hd];
    float self_l = lrelu_f(as1[(size_t)i * 8 + hd] + ad);

    float m = 0.f, den = 0.f;
    if (t < 8) {
        float adh = ad1[(size_t)i * 8 + t];
        m = lrelu_f(as1[(size_t)i * 8 + t] + adh);
        for (int k = k0; k < k1; ++k) {
            int s = csr[k];
            m = fmaxf(m, lrelu_f(as1[(size_t)s * 8 + t] + adh));
        }
        den = expf(lrelu_f(as1[(size_t)i * 8 + t] + adh) - m);
        for (int k = k0; k < k1; ++k) {
            int s = csr[k];
            den += expf(lrelu_f(as1[(size_t)s * 8 + t] + adh) - m);
        }
    }
    float mh  = __shfl(m, hd, 64);
    float inv = 1.f / (__shfl(den, hd, 64) + 1e-16f);

    float acc = expf(self_l - mh) * inv * z1[(size_t)i * 64 + t];
    for (int k = k0; k < k1; ++k) {
        int s = csr[k];
        float w = expf(lrelu_f(as1[(size_t)s * 8 + hd] + ad) - mh) * inv;
        acc += w * z1[(size_t)s * 64 + t];
    }
    h2[(size_t)i * 64 + t] = elu_f(acc + b1[t]);
}

__global__ void k_gat2attn(const float* __restrict__ z2, const float* __restrict__ as2,
                           const float* __restrict__ ad2, const float* __restrict__ b2,
                           const int* __restrict__ offsets, const int* __restrict__ csr,
                           float* __restrict__ h3) {
    int i = blockIdx.x;
    int t = threadIdx.x;     // 0..63
    int k0 = offsets[i], k1 = offsets[i + 1];
    float ad = ad2[i];
    float self_l = lrelu_f(as2[i] + ad);
    float m = (t == 0) ? self_l : -1e30f;
    for (int k = k0 + t; k < k1; k += 64) m = fmaxf(m, lrelu_f(as2[csr[k]] + ad));
    #pragma unroll
    for (int d = 32; d >= 1; d >>= 1) m = fmaxf(m, __shfl_xor(m, d, 64));
    float ds = (t == 0) ? expf(self_l - m) : 0.f;
    for (int k = k0 + t; k < k1; k += 64) ds += expf(lrelu_f(as2[csr[k]] + ad) - m);
    #pragma unroll
    for (int d = 32; d >= 1; d >>= 1) ds += __shfl_xor(ds, d, 64);
    float inv = 1.f / (ds + 1e-16f);
    float acc = expf(self_l - m) * inv * z2[(size_t)i * 64 + t];
    for (int k = k0; k < k1; ++k) {
        int s = csr[k];
        float w = expf(lrelu_f(as2[s] + ad) - m) * inv;
        acc += w * z2[(size_t)s * 64 + t];
    }
    h3[(size_t)i * 64 + t] = acc + b2[t];
}

// ---------------- final mean + linear ----------------
__global__ void k_reduce(const float* __restrict__ h3, const float* __restrict__ Wr,
                         float* __restrict__ red) {
    __shared__ float lds[4];
    int tid = threadIdx.x;
    long long idx = (long long)blockIdx.x * blockDim.x + tid;
    long long total = (long long)N_NODES * 64;
    long long stride = (long long)gridDim.x * blockDim.x;
    float acc = 0.f;
    for (long long p = idx; p < total; p += stride)
        acc += h3[p] * Wr[p & 63];
    #pragma unroll
    for (int d = 32; d >= 1; d >>= 1) acc += __shfl_down(acc, d, 64);
    if ((tid & 63) == 0) lds[tid >> 6] = acc;
    __syncthreads();
    if (tid == 0) {
        float s = lds[0] + lds[1] + lds[2] + lds[3];
        atomicAdd(red, s);
    }
}

__global__ void k_finalize(const float* __restrict__ red, const float* __restrict__ br,
                           float* __restrict__ out) {
    out[0] = red[0] * (1.0f / N_NODES) + br[0];
}

extern "C" void kernel_launch(void* const* d_in, const int* in_sizes, int n_in,
                              void* d_out, int out_size, void* d_ws, size_t ws_size,
                              hipStream_t stream) {
    const float* x      = (const float*)d_in[0];
    const int*   edges  = (const int*)d_in[1];
    const float* W_rel  = (const float*)d_in[2];
    const float* b_rel  = (const float*)d_in[3];
    const float* W_root = (const float*)d_in[4];
    const float* W1     = (const float*)d_in[5];
    const float* a1s    = (const float*)d_in[6];
    const float* a1d    = (const float*)d_in[7];
    const float* b1     = (const float*)d_in[8];
    const float* W2     = (const float*)d_in[9];
    const float* a2s    = (const float*)d_in[10];
    const float* a2d    = (const float*)d_in[11];
    const float* b2     = (const float*)d_in[12];
    const float* Wr     = (const float*)d_in[13];
    const float* br     = (const float*)d_in[14];
    float* out = (float*)d_out;

    const int* src = edges;
    const int* dst = edges + N_EDGES;

    char* ws = (char*)d_ws;
    size_t p = 0;
    auto alloc = [&](size_t bytes) -> void* {
        void* r = ws + p;
        p = (p + bytes + 255) & ~(size_t)255;
        return r;
    };
    int*   counts  = (int*)alloc((size_t)N_NODES * 4);
    int*   offsets = (int*)alloc((size_t)(N_NODES + 1) * 4);
    int*   cursor  = (int*)alloc((size_t)N_NODES * 4);
    int*   csr     = (int*)alloc((size_t)N_EDGES * 4);
    float* nbr     = (float*)alloc((size_t)N_NODES * 128 * 4);
    float* h       = (float*)alloc((size_t)N_NODES * 128 * 4);
    float* z1      = (float*)alloc((size_t)N_NODES * 64 * 4);
    float* as1     = (float*)alloc((size_t)N_NODES * 8 * 4);
    float* ad1     = (float*)alloc((size_t)N_NODES * 8 * 4);
    float* h2      = (float*)alloc((size_t)N_NODES * 64 * 4);
    float* z2      = (float*)alloc((size_t)N_NODES * 64 * 4);
    float* as2     = (float*)alloc((size_t)N_NODES * 4);
    float* ad2     = (float*)alloc((size_t)N_NODES * 4);
    float* red     = (float*)alloc(4);
    float* h3      = nbr;   // reuse: nbr dead after k_linear1

    hipMemsetAsync(counts, 0, (size_t)N_NODES * 4, stream);
    hipMemsetAsync(red, 0, 4, stream);

    const int MB = (N_NODES + 63) / 64;   // 782

    k_count   <<<(N_EDGES + 255) / 256, 256, 0, stream>>>(dst, counts);
    k_scan    <<<1, 1024, 0, stream>>>(counts, offsets, cursor);
    k_scatter <<<(N_EDGES + 255) / 256, 256, 0, stream>>>(src, dst, cursor, csr);
    k_gather  <<<N_NODES, 128, 0, stream>>>(x, offsets, csr, nbr);
    k_linear1 <<<MB, 256, 0, stream>>>(x, nbr, W_rel, b_rel, W_root, h);
    k_gemm64<128><<<MB, 256, 0, stream>>>(h, W1, z1);
    k_alpha1  <<<(N_NODES + 3) / 4, 256, 0, stream>>>(z1, a1s, a1d, as1, ad1);
    k_gat1attn<<<N_NODES, 64, 0, stream>>>(z1, as1, ad1, b1, offsets, csr, h2);
    k_gemm64<64><<<MB, 256, 0, stream>>>(h2, W2, z2);
    k_alpha2  <<<(N_NODES + 3) / 4, 256, 0, stream>>>(z2, a2s, a2d, as2, ad2);
    k_gat2attn<<<N_NODES, 64, 0, stream>>>(z2, as2, ad2, b2, offsets, csr, h3);
    k_reduce  <<<256, 256, 0, stream>>>(h3, Wr, red);
    k_finalize<<<1, 1, 0, stream>>>(red, br, out);
}

// Round 3
// 596.083 us; speedup vs baseline: 1.7697x; 1.2365x over previous
//
#include <hip/hip_runtime.h>
#include <hip/hip_bf16.h>
#include <math.h>

#define N_NODES 50000
#define N_EDGES 800000
#define F_IN 128

typedef __attribute__((ext_vector_type(8))) short bf16x8;
typedef __attribute__((ext_vector_type(4))) float f32x4;
typedef unsigned long long ull;

__device__ __forceinline__ float elu_f(float x)   { return x > 0.f ? x : expm1f(x); }
__device__ __forceinline__ float lrelu_f(float x) { return x > 0.f ? x : 0.2f * x; }
__device__ __forceinline__ int   clampN(int v)    { return v < 0 ? 0 : (v >= N_NODES ? N_NODES - 1 : v); }
__device__ __forceinline__ float bits2f(unsigned int u) { union { unsigned int u; float f; } x; x.u = u; return x.f; }
__device__ __forceinline__ unsigned short f2bfbits(float f) {
    __hip_bfloat16 b = __float2bfloat16(f);
    return __builtin_bit_cast(unsigned short, b);
}

// ---------------- CSR build ----------------
__global__ void k_count(const int* __restrict__ dst, int* __restrict__ counts) {
    int e = blockIdx.x * blockDim.x + threadIdx.x;
    if (e < N_EDGES) atomicAdd(&counts[clampN(dst[e])], 1);
}

__global__ void k_scan(const int* __restrict__ counts, int* __restrict__ offsets,
                       int* __restrict__ cursor) {
    __shared__ int wsum[16];
    __shared__ int wbase[16];
    __shared__ int s_base;
    int tid = threadIdx.x;
    int lane = tid & 63, wid = tid >> 6;
    if (tid == 0) s_base = 0;
    __syncthreads();
    for (int start = 0; start < N_NODES; start += 1024) {
        int i = start + tid;
        int v = (i < N_NODES) ? counts[i] : 0;
        int x = v;
        #pragma unroll
        for (int d = 1; d < 64; d <<= 1) {
            int t = __shfl_up(x, d, 64);
            if (lane >= d) x += t;
        }
        if (lane == 63) wsum[wid] = x;
        __syncthreads();
        if (tid == 0) {
            int b = s_base;
            for (int w = 0; w < 16; ++w) { wbase[w] = b; b += wsum[w]; }
            s_base = b;
        }
        __syncthreads();
        if (i < N_NODES) {
            int excl = wbase[wid] + x - v;
            offsets[i] = excl;
            cursor[i]  = excl;
        }
        __syncthreads();
    }
    if (tid == 0) offsets[N_NODES] = s_base;
}

__global__ void k_scatter(const int* __restrict__ src, const int* __restrict__ dst,
                          int* __restrict__ cursor, int* __restrict__ csr) {
    int e = blockIdx.x * blockDim.x + threadIdx.x;
    if (e < N_EDGES) {
        int d = clampN(dst[e]);
        int pos = atomicAdd(&cursor[d], 1);
        csr[pos] = clampN(src[e]);
    }
}

// ---------------- casts ----------------
// x fp32 -> bf16 into second half of Abuf rows: Abuf[i][128..256) = x[i][:]
__global__ void k_castx(const float* __restrict__ x, __hip_bfloat16* __restrict__ Abuf) {
    int id = blockIdx.x * 256 + threadIdx.x;        // covers 50000*32
    if (id >= N_NODES * 32) return;
    int i = id >> 5, c4 = (id & 31) * 4;
    float4 v = *(const float4*)&x[(size_t)i * 128 + c4];
    ull p = (ull)f2bfbits(v.x) | ((ull)f2bfbits(v.y) << 16)
          | ((ull)f2bfbits(v.z) << 32) | ((ull)f2bfbits(v.w) << 48);
    *(ull*)&Abuf[(size_t)i * 256 + 128 + c4] = p;
}

// weights: Wc[128][256] = [W_rel | W_root]; W1b[64][128]; W2b[64][64]
__global__ void k_castw(const float* __restrict__ W_rel, const float* __restrict__ W_root,
                        const float* __restrict__ W1, const float* __restrict__ W2,
                        __hip_bfloat16* __restrict__ Wc, __hip_bfloat16* __restrict__ W1b,
                        __hip_bfloat16* __restrict__ W2b) {
    int id = blockIdx.x * 256 + threadIdx.x;
    if (id < 32768) {
        int cc = id >> 8, k = id & 255;
        float v = (k < 128) ? W_rel[cc * 128 + k] : W_root[cc * 128 + (k - 128)];
        Wc[id] = __float2bfloat16(v);
    } else if (id < 32768 + 8192) {
        int j = id - 32768;
        W1b[j] = __float2bfloat16(W1[j]);
    } else if (id < 32768 + 8192 + 4096) {
        int j = id - 32768 - 8192;
        W2b[j] = __float2bfloat16(W2[j]);
    }
}

// ---------------- GraphConv gather (bf16 in/out), 4 nodes per block ----------------
__global__ __launch_bounds__(256) void k_gather(const unsigned int* __restrict__ Abuf_u32,
                                                const int* __restrict__ offsets,
                                                const int* __restrict__ csr,
                                                unsigned int* __restrict__ out_u32) {
    int i = blockIdx.x * 4 + (threadIdx.x >> 6);
    if (i >= N_NODES) return;
    int l = threadIdx.x & 63;                        // u32 lane: channels 2l, 2l+1
    int k0 = offsets[i], k1 = offsets[i + 1];
    float a0 = 0.f, a1 = 0.f;
    for (int k = k0; k < k1; ++k) {
        unsigned int u = Abuf_u32[(size_t)csr[k] * 128 + 64 + l];   // x-half
        a0 += bits2f(u << 16);
        a1 += bits2f(u & 0xffff0000u);
    }
    out_u32[(size_t)i * 128 + l] = ((unsigned int)f2bfbits(a1) << 16) | f2bfbits(a0);
}

// ---------------- MFMA GEMM: Out[M x N] = act(A[M x K] @ W[N x K]^T + bias) ----------------
// 256 thr = 4 waves; wave handles 16 rows x N cols. No LDS, fragments straight from global.
template<int K, int N, bool ELU, bool BIAS>
__global__ __launch_bounds__(256) void k_gemm(const __hip_bfloat16* __restrict__ A,
                                              const __hip_bfloat16* __restrict__ W,
                                              const float* __restrict__ bias,
                                              __hip_bfloat16* __restrict__ Out) {
    constexpr int NT = N / 16;
    int lane = threadIdx.x & 63, wave = threadIdx.x >> 6;
    int quad = lane >> 4, l16 = lane & 15;
    int rowA = blockIdx.x * 64 + wave * 16 + l16;
    int rowAc = rowA < N_NODES ? rowA : N_NODES - 1;
    const short* Ap  = (const short*)A + (size_t)rowAc * K + quad * 8;
    const short* Wp0 = (const short*)W + (size_t)l16 * K + quad * 8;
    f32x4 acc[NT];
    #pragma unroll
    for (int t = 0; t < NT; ++t) acc[t] = (f32x4){0.f, 0.f, 0.f, 0.f};
    #pragma unroll
    for (int k0 = 0; k0 < K; k0 += 32) {
        bf16x8 a = *(const bf16x8*)(Ap + k0);
        #pragma unroll
        for (int nt = 0; nt < NT; ++nt) {
            bf16x8 b = *(const bf16x8*)(Wp0 + (size_t)nt * 16 * K + k0);
            acc[nt] = __builtin_amdgcn_mfma_f32_16x16x32_bf16(a, b, acc[nt], 0, 0, 0);
        }
    }
    // C/D layout: col = lane&15, row = quad*4 + reg   [verified m89/m91]
    int mbase = blockIdx.x * 64 + wave * 16 + quad * 4;
    #pragma unroll
    for (int nt = 0; nt < NT; ++nt) {
        int col = nt * 16 + l16;
        float bv = BIAS ? bias[col] : 0.f;
        #pragma unroll
        for (int r = 0; r < 4; ++r) {
            int m = mbase + r;
            if (m < N_NODES) {
                float v = acc[nt][r] + bv;
                if (ELU) v = elu_f(v);
                Out[(size_t)m * N + col] = __float2bfloat16(v);
            }
        }
    }
}

// ---------------- alpha scalars ----------------
__global__ __launch_bounds__(256) void k_alpha1(const __hip_bfloat16* __restrict__ z1,
                                                const float* __restrict__ a_src,
                                                const float* __restrict__ a_dst,
                                                float* __restrict__ as1, float* __restrict__ ad1) {
    int i = blockIdx.x * 4 + (threadIdx.x >> 6);
    if (i >= N_NODES) return;
    int c = threadIdx.x & 63;
    float v = __bfloat162float(z1[(size_t)i * 64 + c]);
    float ps = v * a_src[c];
    float pd = v * a_dst[c];
    #pragma unroll
    for (int d = 4; d >= 1; d >>= 1) {
        ps += __shfl_down(ps, d, 8);
        pd += __shfl_down(pd, d, 8);
    }
    if ((c & 7) == 0) {
        as1[(size_t)i * 8 + (c >> 3)] = ps;
        ad1[(size_t)i * 8 + (c >> 3)] = pd;
    }
}

__global__ __launch_bounds__(256) void k_alpha2(const __hip_bfloat16* __restrict__ z2,
                                                const float* __restrict__ a_src,
                                                const float* __restrict__ a_dst,
                                                float* __restrict__ as2, float* __restrict__ ad2) {
    int i = blockIdx.x * 4 + (threadIdx.x >> 6);
    if (i >= N_NODES) return;
    int c = threadIdx.x & 63;
    float v = __bfloat162float(z2[(size_t)i * 64 + c]);
    float ps = v * a_src[c];
    float pd = v * a_dst[c];
    #pragma unroll
    for (int d = 32; d >= 1; d >>= 1) {
        ps += __shfl_down(ps, d, 64);
        pd += __shfl_down(pd, d, 64);
    }
    if (c == 0) { as2[i] = ps; ad2[i] = pd; }
}

// ---------------- GAT1 attention: 8 heads x 8 ch, 4 nodes/block ----------------
__global__ __launch_bounds__(256) void k_gat1attn(const __hip_bfloat16* __restrict__ z1,
                                                  const float* __restrict__ as1,
                                                  const float* __restrict__ ad1,
                                                  const float* __restrict__ b1,
                                                  const int* __restrict__ offsets,
                                                  const int* __restrict__ csr,
                                                  __hip_bfloat16* __restrict__ h2) {
    int i = blockIdx.x * 4 + (threadIdx.x >> 6);
    if (i >= N_NODES) return;
    int t = threadIdx.x & 63;
    int k0 = offsets[i], k1 = offsets[i + 1];
    // passes 1&2: lane = (head hh = t&7, edge slot sl = t>>3)
    int hh = t & 7, sl = t >> 3;
    float adh   = ad1[(size_t)i * 8 + hh];
    float selfl = lrelu_f(as1[(size_t)i * 8 + hh] + adh);
    float m = (sl == 0) ? selfl : -1e30f;
    for (int k = k0 + sl; k < k1; k += 8)
        m = fmaxf(m, lrelu_f(as1[(size_t)csr[k] * 8 + hh] + adh));
    #pragma unroll
    for (int d = 8; d < 64; d <<= 1) m = fmaxf(m, __shfl_xor(m, d, 64));
    float den = (sl == 0) ? __expf(selfl - m) : 0.f;
    for (int k = k0 + sl; k < k1; k += 8)
        den += __expf(lrelu_f(as1[(size_t)csr[k] * 8 + hh] + adh) - m);
    #pragma unroll
    for (int d = 8; d < 64; d <<= 1) den += __shfl_xor(den, d, 64);
    // pass 3: lane = channel t, head hd = t>>3; head stats live in lane hd (hh==hd, sl==0)
    int hd = t >> 3;
    float mh  = __shfl(m, hd, 64);
    float inv = 1.f / (__shfl(den, hd, 64) + 1e-16f);
    float ad  = __shfl(adh, hd, 64);
    float slf = __shfl(selfl, hd, 64);
    float acc = __expf(slf - mh) * inv * __bfloat162float(z1[(size_t)i * 64 + t]);
    for (int k = k0; k < k1; ++k) {
        int s = csr[k];
        float w = __expf(lrelu_f(as1[(size_t)s * 8 + hd] + ad) - mh) * inv;
        acc += w * __bfloat162float(z1[(size_t)s * 64 + t]);
    }
    h2[(size_t)i * 64 + t] = __float2bfloat16(elu_f(acc + b1[t]));
}

// ---------------- GAT2 attention: 1 head x 64 ch, 4 nodes/block ----------------
__global__ __launch_bounds__(256) void k_gat2attn(const __hip_bfloat16* __restrict__ z2,
                                                  const float* __restrict__ as2,
                                                  const float* __restrict__ ad2,
                                                  const float* __restrict__ b2,
                                                  const int* __restrict__ offsets,
                                                  const int* __restrict__ csr,
                                                  float* __restrict__ h3) {
    int i = blockIdx.x * 4 + (threadIdx.x >> 6);
    if (i >= N_NODES) return;
    int t = threadIdx.x & 63;
    int k0 = offsets[i], k1 = offsets[i + 1];
    float ad = ad2[i];
    float selfl = lrelu_f(as2[i] + ad);
    float m = (t == 0) ? selfl : -1e30f;
    for (int k = k0 + t; k < k1; k += 64) m = fmaxf(m, lrelu_f(as2[csr[k]] + ad));
    #pragma unroll
    for (int d = 32; d >= 1; d >>= 1) m = fmaxf(m, __shfl_xor(m, d, 64));
    float ds = (t == 0) ? __expf(selfl - m) : 0.f;
    for (int k = k0 + t; k < k1; k += 64) ds += __expf(lrelu_f(as2[csr[k]] + ad) - m);
    #pragma unroll
    for (int d = 32; d >= 1; d >>= 1) ds += __shfl_xor(ds, d, 64);
    float inv = 1.f / (ds + 1e-16f);
    float acc = __expf(selfl - m) * inv * __bfloat162float(z2[(size_t)i * 64 + t]);
    for (int k = k0; k < k1; ++k) {
        int s = csr[k];
        float w = __expf(lrelu_f(as2[s] + ad) - m) * inv;
        acc += w * __bfloat162float(z2[(size_t)s * 64 + t]);
    }
    h3[(size_t)i * 64 + t] = acc + b2[t];
}

// ---------------- final mean + linear ----------------
__global__ void k_reduce(const float* __restrict__ h3, const float* __restrict__ Wr,
                         float* __restrict__ red) {
    __shared__ float lds[4];
    int tid = threadIdx.x;
    long long idx = (long long)blockIdx.x * blockDim.x + tid;
    long long total = (long long)N_NODES * 64;
    long long stride = (long long)gridDim.x * blockDim.x;
    float acc = 0.f;
    for (long long p = idx; p < total; p += stride)
        acc += h3[p] * Wr[p & 63];
    #pragma unroll
    for (int d = 32; d >= 1; d >>= 1) acc += __shfl_down(acc, d, 64);
    if ((tid & 63) == 0) lds[tid >> 6] = acc;
    __syncthreads();
    if (tid == 0) {
        float s = lds[0] + lds[1] + lds[2] + lds[3];
        atomicAdd(red, s);
    }
}

__global__ void k_finalize(const float* __restrict__ red, const float* __restrict__ br,
                           float* __restrict__ out) {
    out[0] = red[0] * (1.0f / N_NODES) + br[0];
}

extern "C" void kernel_launch(void* const* d_in, const int* in_sizes, int n_in,
                              void* d_out, int out_size, void* d_ws, size_t ws_size,
                              hipStream_t stream) {
    const float* x      = (const float*)d_in[0];
    const int*   edges  = (const int*)d_in[1];
    const float* W_rel  = (const float*)d_in[2];
    const float* b_rel  = (const float*)d_in[3];
    const float* W_root = (const float*)d_in[4];
    const float* W1     = (const float*)d_in[5];
    const float* a1s    = (const float*)d_in[6];
    const float* a1d    = (const float*)d_in[7];
    const float* b1     = (const float*)d_in[8];
    const float* W2     = (const float*)d_in[9];
    const float* a2s    = (const float*)d_in[10];
    const float* a2d    = (const float*)d_in[11];
    const float* b2     = (const float*)d_in[12];
    const float* Wr     = (const float*)d_in[13];
    const float* br     = (const float*)d_in[14];
    float* out = (float*)d_out;

    const int* src = edges;
    const int* dst = edges + N_EDGES;

    char* ws = (char*)d_ws;
    size_t p = 0;
    auto alloc = [&](size_t bytes) -> void* {
        void* r = ws + p;
        p = (p + bytes + 255) & ~(size_t)255;
        return r;
    };
    int*   counts  = (int*)alloc((size_t)N_NODES * 4);
    int*   offsets = (int*)alloc((size_t)(N_NODES + 1) * 4);
    int*   cursor  = (int*)alloc((size_t)N_NODES * 4);
    int*   csr     = (int*)alloc((size_t)N_EDGES * 4);
    __hip_bfloat16* Abuf = (__hip_bfloat16*)alloc((size_t)N_NODES * 256 * 2);  // [nbr | x]
    __hip_bfloat16* Wc   = (__hip_bfloat16*)alloc((size_t)128 * 256 * 2);
    __hip_bfloat16* W1b  = (__hip_bfloat16*)alloc((size_t)64 * 128 * 2);
    __hip_bfloat16* W2b  = (__hip_bfloat16*)alloc((size_t)64 * 64 * 2);
    __hip_bfloat16* h    = (__hip_bfloat16*)alloc((size_t)N_NODES * 128 * 2);
    __hip_bfloat16* z1b  = (__hip_bfloat16*)alloc((size_t)N_NODES * 64 * 2);
    float* as1 = (float*)alloc((size_t)N_NODES * 8 * 4);
    float* ad1 = (float*)alloc((size_t)N_NODES * 8 * 4);
    __hip_bfloat16* h2b  = (__hip_bfloat16*)alloc((size_t)N_NODES * 64 * 2);
    __hip_bfloat16* z2b  = (__hip_bfloat16*)alloc((size_t)N_NODES * 64 * 2);
    float* as2 = (float*)alloc((size_t)N_NODES * 4);
    float* ad2 = (float*)alloc((size_t)N_NODES * 4);
    float* h3  = (float*)alloc((size_t)N_NODES * 64 * 4);
    float* red = (float*)alloc(4);

    hipMemsetAsync(counts, 0, (size_t)N_NODES * 4, stream);
    hipMemsetAsync(red, 0, 4, stream);

    const int MB = (N_NODES + 63) / 64;     // 782
    const int NB4 = (N_NODES + 3) / 4;      // 12500

    k_count  <<<(N_EDGES + 255) / 256, 256, 0, stream>>>(dst, counts);
    k_scan   <<<1, 1024, 0, stream>>>(counts, offsets, cursor);
    k_scatter<<<(N_EDGES + 255) / 256, 256, 0, stream>>>(src, dst, cursor, csr);
    k_castx  <<<(N_NODES * 32 + 255) / 256, 256, 0, stream>>>(x, Abuf);
    k_castw  <<<(32768 + 8192 + 4096 + 255) / 256, 256, 0, stream>>>(W_rel, W_root, W1, W2, Wc, W1b, W2b);
    k_gather <<<NB4, 256, 0, stream>>>((const unsigned int*)Abuf, offsets, csr, (unsigned int*)Abuf);
    k_gemm<256, 128, true,  true ><<<MB, 256, 0, stream>>>(Abuf, Wc, b_rel, h);
    k_gemm<128, 64,  false, false><<<MB, 256, 0, stream>>>(h, W1b, nullptr, z1b);
    k_alpha1 <<<NB4, 256, 0, stream>>>(z1b, a1s, a1d, as1, ad1);
    k_gat1attn<<<NB4, 256, 0, stream>>>(z1b, as1, ad1, b1, offsets, csr, h2b);
    k_gemm<64, 64, false, false><<<MB, 256, 0, stream>>>(h2b, W2b, nullptr, z2b);
    k_alpha2 <<<NB4, 256, 0, stream>>>(z2b, a2s, a2d, as2, ad2);
    k_gat2attn<<<NB4, 256, 0, stream>>>(z2b, as2, ad2, b2, offsets, csr, h3);
    k_reduce <<<256, 256, 0, stream>>>(h3, Wr, red);
    k_finalize<<<1, 1, 0, stream>>>(red, br, out);
}

// Round 4
// 479.952 us; speedup vs baseline: 2.1979x; 1.2420x over previous
//
#include <hip/hip_runtime.h>
#include <hip/hip_bf16.h>
#include <math.h>

#define N_NODES 50000
#define N_EDGES 800000
#define F_IN 128

typedef __attribute__((ext_vector_type(8))) short bf16x8;
typedef __attribute__((ext_vector_type(4))) float f32x4;
typedef unsigned long long ull;

__device__ __forceinline__ float elu_f(float x)   { return x > 0.f ? x : expm1f(x); }
__device__ __forceinline__ float lrelu_f(float x) { return x > 0.f ? x : 0.2f * x; }
__device__ __forceinline__ int   clampN(int v)    { return v < 0 ? 0 : (v >= N_NODES ? N_NODES - 1 : v); }
__device__ __forceinline__ float bits2f(unsigned int u) { union { unsigned int u; float f; } x; x.u = u; return x.f; }
__device__ __forceinline__ unsigned short f2bfbits(float f) {
    __hip_bfloat16 b = __float2bfloat16(f);
    return __builtin_bit_cast(unsigned short, b);
}

// ---------------- CSR build ----------------
__global__ void k_count(const int* __restrict__ dst, int* __restrict__ counts) {
    int e = blockIdx.x * blockDim.x + threadIdx.x;
    if (e < N_EDGES) atomicAdd(&counts[clampN(dst[e])], 1);
}

__global__ void k_scan(const int* __restrict__ counts, int* __restrict__ offsets,
                       int* __restrict__ cursor) {
    __shared__ int wsum[16];
    __shared__ int wbase[16];
    __shared__ int s_base;
    int tid = threadIdx.x;
    int lane = tid & 63, wid = tid >> 6;
    if (tid == 0) s_base = 0;
    __syncthreads();
    for (int start = 0; start < N_NODES; start += 1024) {
        int i = start + tid;
        int v = (i < N_NODES) ? counts[i] : 0;
        int x = v;
        #pragma unroll
        for (int d = 1; d < 64; d <<= 1) {
            int t = __shfl_up(x, d, 64);
            if (lane >= d) x += t;
        }
        if (lane == 63) wsum[wid] = x;
        __syncthreads();
        if (tid == 0) {
            int b = s_base;
            for (int w = 0; w < 16; ++w) { wbase[w] = b; b += wsum[w]; }
            s_base = b;
        }
        __syncthreads();
        if (i < N_NODES) {
            int excl = wbase[wid] + x - v;
            offsets[i] = excl;
            cursor[i]  = excl;
        }
        __syncthreads();
    }
    if (tid == 0) offsets[N_NODES] = s_base;
}

__global__ void k_scatter(const int* __restrict__ src, const int* __restrict__ dst,
                          int* __restrict__ cursor, int* __restrict__ csr) {
    int e = blockIdx.x * blockDim.x + threadIdx.x;
    if (e < N_EDGES) {
        int d = clampN(dst[e]);
        int pos = atomicAdd(&cursor[d], 1);
        csr[pos] = clampN(src[e]);
    }
}

// ---------------- casts ----------------
__global__ void k_castx(const float* __restrict__ x, __hip_bfloat16* __restrict__ Abuf) {
    int id = blockIdx.x * 256 + threadIdx.x;        // covers 50000*32
    if (id >= N_NODES * 32) return;
    int i = id >> 5, c4 = (id & 31) * 4;
    float4 v = *(const float4*)&x[(size_t)i * 128 + c4];
    ull p = (ull)f2bfbits(v.x) | ((ull)f2bfbits(v.y) << 16)
          | ((ull)f2bfbits(v.z) << 32) | ((ull)f2bfbits(v.w) << 48);
    *(ull*)&Abuf[(size_t)i * 256 + 128 + c4] = p;
}

__global__ void k_castw(const float* __restrict__ W_rel, const float* __restrict__ W_root,
                        const float* __restrict__ W1, const float* __restrict__ W2,
                        __hip_bfloat16* __restrict__ Wc, __hip_bfloat16* __restrict__ W1b,
                        __hip_bfloat16* __restrict__ W2b) {
    int id = blockIdx.x * 256 + threadIdx.x;
    if (id < 32768) {
        int cc = id >> 8, k = id & 255;
        float v = (k < 128) ? W_rel[cc * 128 + k] : W_root[cc * 128 + (k - 128)];
        Wc[id] = __float2bfloat16(v);
    } else if (id < 32768 + 8192) {
        int j = id - 32768;
        W1b[j] = __float2bfloat16(W1[j]);
    } else if (id < 32768 + 8192 + 4096) {
        int j = id - 32768 - 8192;
        W2b[j] = __float2bfloat16(W2[j]);
    }
}

// ---------------- GraphConv gather (bf16 in/out), 4 nodes per block ----------------
__global__ __launch_bounds__(256) void k_gather(const unsigned int* __restrict__ Abuf_u32,
                                                const int* __restrict__ offsets,
                                                const int* __restrict__ csr,
                                                unsigned int* __restrict__ out_u32) {
    int i = blockIdx.x * 4 + (threadIdx.x >> 6);
    if (i >= N_NODES) return;
    int l = threadIdx.x & 63;                        // u32 lane: channels 2l, 2l+1
    int k0 = offsets[i], k1 = offsets[i + 1];
    float a0 = 0.f, a1 = 0.f;
    int k = k0;
    for (; k + 1 < k1; k += 2) {
        int s0 = csr[k], s1 = csr[k + 1];
        unsigned int u0 = Abuf_u32[(size_t)s0 * 128 + 64 + l];
        unsigned int u1 = Abuf_u32[(size_t)s1 * 128 + 64 + l];
        a0 += bits2f(u0 << 16) + bits2f(u1 << 16);
        a1 += bits2f(u0 & 0xffff0000u) + bits2f(u1 & 0xffff0000u);
    }
    if (k < k1) {
        unsigned int u = Abuf_u32[(size_t)csr[k] * 128 + 64 + l];
        a0 += bits2f(u << 16);
        a1 += bits2f(u & 0xffff0000u);
    }
    out_u32[(size_t)i * 128 + l] = ((unsigned int)f2bfbits(a1) << 16) | f2bfbits(a0);
}

// ---------------- MFMA GEMM ----------------
template<int K, int N, bool ELU, bool BIAS>
__global__ __launch_bounds__(256) void k_gemm(const __hip_bfloat16* __restrict__ A,
                                              const __hip_bfloat16* __restrict__ W,
                                              const float* __restrict__ bias,
                                              __hip_bfloat16* __restrict__ Out) {
    constexpr int NT = N / 16;
    int lane = threadIdx.x & 63, wave = threadIdx.x >> 6;
    int quad = lane >> 4, l16 = lane & 15;
    int rowA = blockIdx.x * 64 + wave * 16 + l16;
    int rowAc = rowA < N_NODES ? rowA : N_NODES - 1;
    const short* Ap  = (const short*)A + (size_t)rowAc * K + quad * 8;
    const short* Wp0 = (const short*)W + (size_t)l16 * K + quad * 8;
    f32x4 acc[NT];
    #pragma unroll
    for (int t = 0; t < NT; ++t) acc[t] = (f32x4){0.f, 0.f, 0.f, 0.f};
    #pragma unroll
    for (int k0 = 0; k0 < K; k0 += 32) {
        bf16x8 a = *(const bf16x8*)(Ap + k0);
        #pragma unroll
        for (int nt = 0; nt < NT; ++nt) {
            bf16x8 b = *(const bf16x8*)(Wp0 + (size_t)nt * 16 * K + k0);
            acc[nt] = __builtin_amdgcn_mfma_f32_16x16x32_bf16(a, b, acc[nt], 0, 0, 0);
        }
    }
    int mbase = blockIdx.x * 64 + wave * 16 + quad * 4;
    #pragma unroll
    for (int nt = 0; nt < NT; ++nt) {
        int col = nt * 16 + l16;
        float bv = BIAS ? bias[col] : 0.f;
        #pragma unroll
        for (int r = 0; r < 4; ++r) {
            int m = mbase + r;
            if (m < N_NODES) {
                float v = acc[nt][r] + bv;
                if (ELU) v = elu_f(v);
                Out[(size_t)m * N + col] = __float2bfloat16(v);
            }
        }
    }
}

// ---------------- alpha scalars ----------------
__global__ __launch_bounds__(256) void k_alpha1(const __hip_bfloat16* __restrict__ z1,
                                                const float* __restrict__ a_src,
                                                const float* __restrict__ a_dst,
                                                float* __restrict__ as1, float* __restrict__ ad1) {
    int i = blockIdx.x * 4 + (threadIdx.x >> 6);
    if (i >= N_NODES) return;
    int c = threadIdx.x & 63;
    float v = __bfloat162float(z1[(size_t)i * 64 + c]);
    float ps = v * a_src[c];
    float pd = v * a_dst[c];
    #pragma unroll
    for (int d = 4; d >= 1; d >>= 1) {
        ps += __shfl_down(ps, d, 8);
        pd += __shfl_down(pd, d, 8);
    }
    if ((c & 7) == 0) {
        as1[(size_t)i * 8 + (c >> 3)] = ps;
        ad1[(size_t)i * 8 + (c >> 3)] = pd;
    }
}

__global__ __launch_bounds__(256) void k_alpha2(const __hip_bfloat16* __restrict__ z2,
                                                const float* __restrict__ a_src,
                                                const float* __restrict__ a_dst,
                                                float* __restrict__ as2, float* __restrict__ ad2) {
    int i = blockIdx.x * 4 + (threadIdx.x >> 6);
    if (i >= N_NODES) return;
    int c = threadIdx.x & 63;
    float v = __bfloat162float(z2[(size_t)i * 64 + c]);
    float ps = v * a_src[c];
    float pd = v * a_dst[c];
    #pragma unroll
    for (int d = 32; d >= 1; d >>= 1) {
        ps += __shfl_down(ps, d, 64);
        pd += __shfl_down(pd, d, 64);
    }
    if (c == 0) { as2[i] = ps; ad2[i] = pd; }
}

// ---------------- GAT1 attention: single-pass softmax (no max sub) ----------------
// logits are O(±6): exp is fp32-safe without max subtraction. acc/den fused sweep.
__global__ __launch_bounds__(256) void k_gat1attn(const __hip_bfloat16* __restrict__ z1,
                                                  const float* __restrict__ as1,
                                                  const float* __restrict__ ad1,
                                                  const float* __restrict__ b1,
                                                  const int* __restrict__ offsets,
                                                  const int* __restrict__ csr,
                                                  __hip_bfloat16* __restrict__ h2) {
    int i = blockIdx.x * 4 + (threadIdx.x >> 6);
    if (i >= N_NODES) return;
    int t = threadIdx.x & 63;
    int hd = t >> 3;
    int k0 = offsets[i], k1 = offsets[i + 1];
    float ad = ad1[(size_t)i * 8 + hd];
    float e_self = __expf(lrelu_f(as1[(size_t)i * 8 + hd] + ad));
    float acc = e_self * __bfloat162float(z1[(size_t)i * 64 + t]);
    float den = e_self;
    int k = k0;
    for (; k + 1 < k1; k += 2) {
        int s0 = csr[k], s1 = csr[k + 1];
        float e0 = __expf(lrelu_f(as1[(size_t)s0 * 8 + hd] + ad));
        float e1 = __expf(lrelu_f(as1[(size_t)s1 * 8 + hd] + ad));
        float v0 = __bfloat162float(z1[(size_t)s0 * 64 + t]);
        float v1 = __bfloat162float(z1[(size_t)s1 * 64 + t]);
        acc += e0 * v0 + e1 * v1;
        den += e0 + e1;
    }
    if (k < k1) {
        int s = csr[k];
        float e = __expf(lrelu_f(as1[(size_t)s * 8 + hd] + ad));
        acc += e * __bfloat162float(z1[(size_t)s * 64 + t]);
        den += e;
    }
    h2[(size_t)i * 64 + t] = __float2bfloat16(elu_f(acc / den + b1[t]));
}

// ---------------- GAT2 attention: single-pass softmax ----------------
__global__ __launch_bounds__(256) void k_gat2attn(const __hip_bfloat16* __restrict__ z2,
                                                  const float* __restrict__ as2,
                                                  const float* __restrict__ ad2,
                                                  const float* __restrict__ b2,
                                                  const int* __restrict__ offsets,
                                                  const int* __restrict__ csr,
                                                  float* __restrict__ h3) {
    int i = blockIdx.x * 4 + (threadIdx.x >> 6);
    if (i >= N_NODES) return;
    int t = threadIdx.x & 63;
    int k0 = offsets[i], k1 = offsets[i + 1];
    float ad = ad2[i];
    float e_self = __expf(lrelu_f(as2[i] + ad));
    float acc = e_self * __bfloat162float(z2[(size_t)i * 64 + t]);
    float den = e_self;
    int k = k0;
    for (; k + 1 < k1; k += 2) {
        int s0 = csr[k], s1 = csr[k + 1];
        float e0 = __expf(lrelu_f(as2[s0] + ad));
        float e1 = __expf(lrelu_f(as2[s1] + ad));
        float v0 = __bfloat162float(z2[(size_t)s0 * 64 + t]);
        float v1 = __bfloat162float(z2[(size_t)s1 * 64 + t]);
        acc += e0 * v0 + e1 * v1;
        den += e0 + e1;
    }
    if (k < k1) {
        int s = csr[k];
        float e = __expf(lrelu_f(as2[s] + ad));
        acc += e * __bfloat162float(z2[(size_t)s * 64 + t]);
        den += e;
    }
    h3[(size_t)i * 64 + t] = acc / den + b2[t];
}

// ---------------- final mean + linear ----------------
__global__ void k_reduce(const float* __restrict__ h3, const float* __restrict__ Wr,
                         float* __restrict__ red) {
    __shared__ float lds[4];
    int tid = threadIdx.x;
    long long idx = (long long)blockIdx.x * blockDim.x + tid;
    long long total = (long long)N_NODES * 64;
    long long stride = (long long)gridDim.x * blockDim.x;
    float acc = 0.f;
    for (long long p = idx; p < total; p += stride)
        acc += h3[p] * Wr[p & 63];
    #pragma unroll
    for (int d = 32; d >= 1; d >>= 1) acc += __shfl_down(acc, d, 64);
    if ((tid & 63) == 0) lds[tid >> 6] = acc;
    __syncthreads();
    if (tid == 0) {
        float s = lds[0] + lds[1] + lds[2] + lds[3];
        atomicAdd(red, s);
    }
}

__global__ void k_finalize(const float* __restrict__ red, const float* __restrict__ br,
                           float* __restrict__ out) {
    out[0] = red[0] * (1.0f / N_NODES) + br[0];
}

extern "C" void kernel_launch(void* const* d_in, const int* in_sizes, int n_in,
                              void* d_out, int out_size, void* d_ws, size_t ws_size,
                              hipStream_t stream) {
    const float* x      = (const float*)d_in[0];
    const int*   edges  = (const int*)d_in[1];
    const float* W_rel  = (const float*)d_in[2];
    const float* b_rel  = (const float*)d_in[3];
    const float* W_root = (const float*)d_in[4];
    const float* W1     = (const float*)d_in[5];
    const float* a1s    = (const float*)d_in[6];
    const float* a1d    = (const float*)d_in[7];
    const float* b1     = (const float*)d_in[8];
    const float* W2     = (const float*)d_in[9];
    const float* a2s    = (const float*)d_in[10];
    const float* a2d    = (const float*)d_in[11];
    const float* b2     = (const float*)d_in[12];
    const float* Wr     = (const float*)d_in[13];
    const float* br     = (const float*)d_in[14];
    float* out = (float*)d_out;

    const int* src = edges;
    const int* dst = edges + N_EDGES;

    char* ws = (char*)d_ws;
    size_t p = 0;
    auto alloc = [&](size_t bytes) -> void* {
        void* r = ws + p;
        p = (p + bytes + 255) & ~(size_t)255;
        return r;
    };
    int*   counts  = (int*)alloc((size_t)N_NODES * 4);
    int*   offsets = (int*)alloc((size_t)(N_NODES + 1) * 4);
    int*   cursor  = (int*)alloc((size_t)N_NODES * 4);
    int*   csr     = (int*)alloc((size_t)N_EDGES * 4);
    __hip_bfloat16* Abuf = (__hip_bfloat16*)alloc((size_t)N_NODES * 256 * 2);  // [nbr | x]
    __hip_bfloat16* Wc   = (__hip_bfloat16*)alloc((size_t)128 * 256 * 2);
    __hip_bfloat16* W1b  = (__hip_bfloat16*)alloc((size_t)64 * 128 * 2);
    __hip_bfloat16* W2b  = (__hip_bfloat16*)alloc((size_t)64 * 64 * 2);
    __hip_bfloat16* h    = (__hip_bfloat16*)alloc((size_t)N_NODES * 128 * 2);
    __hip_bfloat16* z1b  = (__hip_bfloat16*)alloc((size_t)N_NODES * 64 * 2);
    float* as1 = (float*)alloc((size_t)N_NODES * 8 * 4);
    float* ad1 = (float*)alloc((size_t)N_NODES * 8 * 4);
    __hip_bfloat16* h2b  = (__hip_bfloat16*)alloc((size_t)N_NODES * 64 * 2);
    __hip_bfloat16* z2b  = (__hip_bfloat16*)alloc((size_t)N_NODES * 64 * 2);
    float* as2 = (float*)alloc((size_t)N_NODES * 4);
    float* ad2 = (float*)alloc((size_t)N_NODES * 4);
    float* h3  = (float*)alloc((size_t)N_NODES * 64 * 4);
    float* red = (float*)alloc(4);

    hipMemsetAsync(counts, 0, (size_t)N_NODES * 4, stream);
    hipMemsetAsync(red, 0, 4, stream);

    const int MB = (N_NODES + 63) / 64;     // 782
    const int NB4 = (N_NODES + 3) / 4;      // 12500

    k_count  <<<(N_EDGES + 255) / 256, 256, 0, stream>>>(dst, counts);
    k_scan   <<<1, 1024, 0, stream>>>(counts, offsets, cursor);
    k_scatter<<<(N_EDGES + 255) / 256, 256, 0, stream>>>(src, dst, cursor, csr);
    k_castx  <<<(N_NODES * 32 + 255) / 256, 256, 0, stream>>>(x, Abuf);
    k_castw  <<<(32768 + 8192 + 4096 + 255) / 256, 256, 0, stream>>>(W_rel, W_root, W1, W2, Wc, W1b, W2b);
    k_gather <<<NB4, 256, 0, stream>>>((const unsigned int*)Abuf, offsets, csr, (unsigned int*)Abuf);
    k_gemm<256, 128, true,  true ><<<MB, 256, 0, stream>>>(Abuf, Wc, b_rel, h);
    k_gemm<128, 64,  false, false><<<MB, 256, 0, stream>>>(h, W1b, nullptr, z1b);
    k_alpha1 <<<NB4, 256, 0, stream>>>(z1b, a1s, a1d, as1, ad1);
    k_gat1attn<<<NB4, 256, 0, stream>>>(z1b, as1, ad1, b1, offsets, csr, h2b);
    k_gemm<64, 64, false, false><<<MB, 256, 0, stream>>>(h2b, W2b, nullptr, z2b);
    k_alpha2 <<<NB4, 256, 0, stream>>>(z2b, a2s, a2d, as2, ad2);
    k_gat2attn<<<NB4, 256, 0, stream>>>(z2b, as2, ad2, b2, offsets, csr, h3);
    k_reduce <<<256, 256, 0, stream>>>(h3, Wr, red);
    k_finalize<<<1, 1, 0, stream>>>(red, br, out);
}

// Round 6
// 442.787 us; speedup vs baseline: 2.3824x; 1.0839x over previous
//
#include <hip/hip_runtime.h>
#include <hip/hip_bf16.h>
#include <math.h>

#define N_NODES 50000
#define N_EDGES 800000
#define F_IN 128
#define NB_SCAN 196   // ceil(50000/256)

typedef __attribute__((ext_vector_type(8))) short bf16x8;
typedef __attribute__((ext_vector_type(4))) float f32x4;
typedef unsigned long long ull;

__device__ __forceinline__ float elu_f(float x)   { return x > 0.f ? x : expm1f(x); }
__device__ __forceinline__ float lrelu_f(float x) { return x > 0.f ? x : 0.2f * x; }
__device__ __forceinline__ int   clampN(int v)    { return v < 0 ? 0 : (v >= N_NODES ? N_NODES - 1 : v); }
__device__ __forceinline__ float bits2f(unsigned int u) { union { unsigned int u; float f; } x; x.u = u; return x.f; }
__device__ __forceinline__ unsigned short f2bfbits(float f) {
    __hip_bfloat16 b = __float2bfloat16(f);
    return __builtin_bit_cast(unsigned short, b);
}

// ---------------- CSR build ----------------
__global__ void k_count(const int* __restrict__ dst, int* __restrict__ counts) {
    int e = blockIdx.x * blockDim.x + threadIdx.x;
    if (e < N_EDGES) atomicAdd(&counts[clampN(dst[e])], 1);
}

// phase A: per-block (256 counts) sum
__global__ __launch_bounds__(256) void k_scanA(const int* __restrict__ counts,
                                               int* __restrict__ part) {
    __shared__ int ws[4];
    int tid = threadIdx.x;
    int i = blockIdx.x * 256 + tid;
    int v = (i < N_NODES) ? counts[i] : 0;
    #pragma unroll
    for (int d = 32; d >= 1; d >>= 1) v += __shfl_down(v, d, 64);
    if ((tid & 63) == 0) ws[tid >> 6] = v;
    __syncthreads();
    if (tid == 0) part[blockIdx.x] = ws[0] + ws[1] + ws[2] + ws[3];
}

// phase B: single block, exclusive scan of NB_SCAN partials
__global__ __launch_bounds__(256) void k_scanB(int* __restrict__ part) {
    __shared__ int wsum[4];
    __shared__ int wbase[4];
    int tid = threadIdx.x;
    int lane = tid & 63, wid = tid >> 6;
    int v = (tid < NB_SCAN) ? part[tid] : 0;
    int x = v;
    #pragma unroll
    for (int d = 1; d < 64; d <<= 1) {
        int t = __shfl_up(x, d, 64);
        if (lane >= d) x += t;
    }
    if (lane == 63) wsum[wid] = x;
    __syncthreads();
    if (tid == 0) {
        int b = 0;
        #pragma unroll
        for (int w = 0; w < 4; ++w) { wbase[w] = b; b += wsum[w]; }
    }
    __syncthreads();
    if (tid < NB_SCAN) part[tid] = wbase[wid] + x - v;
}

// phase C: per-block exclusive scan + base
__global__ __launch_bounds__(256) void k_scanC(const int* __restrict__ counts,
                                               const int* __restrict__ part,
                                               int* __restrict__ offsets,
                                               int* __restrict__ cursor) {
    __shared__ int wsum[4];
    __shared__ int wbase[4];
    int tid = threadIdx.x;
    int lane = tid & 63, wid = tid >> 6;
    int i = blockIdx.x * 256 + tid;
    int v = (i < N_NODES) ? counts[i] : 0;
    int x = v;
    #pragma unroll
    for (int d = 1; d < 64; d <<= 1) {
        int t = __shfl_up(x, d, 64);
        if (lane >= d) x += t;
    }
    if (lane == 63) wsum[wid] = x;
    __syncthreads();
    if (tid == 0) {
        int b = part[blockIdx.x];
        #pragma unroll
        for (int w = 0; w < 4; ++w) { wbase[w] = b; b += wsum[w]; }
    }
    __syncthreads();
    if (i < N_NODES) {
        int excl = wbase[wid] + x - v;
        offsets[i] = excl;
        cursor[i]  = excl;
    }
    if (blockIdx.x == 0 && tid == 0) offsets[N_NODES] = N_EDGES;
}

// scatter: csr[pos]=src, dpos[pos]=dst
__global__ void k_scatter(const int* __restrict__ src, const int* __restrict__ dst,
                          int* __restrict__ cursor, int* __restrict__ csr,
                          int* __restrict__ dpos) {
    int e = blockIdx.x * blockDim.x + threadIdx.x;
    if (e < N_EDGES) {
        int d = clampN(dst[e]);
        int pos = atomicAdd(&cursor[d], 1);
        csr[pos]  = clampN(src[e]);
        dpos[pos] = d;
    }
}

// ---------------- casts ----------------
__global__ void k_castx(const float* __restrict__ x, __hip_bfloat16* __restrict__ Abuf) {
    int id = blockIdx.x * 256 + threadIdx.x;        // covers 50000*32
    if (id >= N_NODES * 32) return;
    int i = id >> 5, c4 = (id & 31) * 4;
    float4 v = *(const float4*)&x[(size_t)i * 128 + c4];
    ull p = (ull)f2bfbits(v.x) | ((ull)f2bfbits(v.y) << 16)
          | ((ull)f2bfbits(v.z) << 32) | ((ull)f2bfbits(v.w) << 48);
    *(ull*)&Abuf[(size_t)i * 256 + 128 + c4] = p;
}

__global__ void k_castw(const float* __restrict__ W_rel, const float* __restrict__ W_root,
                        const float* __restrict__ W1, const float* __restrict__ W2,
                        __hip_bfloat16* __restrict__ Wc, __hip_bfloat16* __restrict__ W1b,
                        __hip_bfloat16* __restrict__ W2b) {
    int id = blockIdx.x * 256 + threadIdx.x;
    if (id < 32768) {
        int cc = id >> 8, k = id & 255;
        float v = (k < 128) ? W_rel[cc * 128 + k] : W_root[cc * 128 + (k - 128)];
        Wc[id] = __float2bfloat16(v);
    } else if (id < 32768 + 8192) {
        int j = id - 32768;
        W1b[j] = __float2bfloat16(W1[j]);
    } else if (id < 32768 + 8192 + 4096) {
        int j = id - 32768 - 8192;
        W2b[j] = __float2bfloat16(W2[j]);
    }
}

// ---------------- GraphConv gather (bf16 in/out), 4 nodes per block, unroll 4 ----------------
__global__ __launch_bounds__(256) void k_gather(const unsigned int* __restrict__ Abuf_u32,
                                                const int* __restrict__ offsets,
                                                const int* __restrict__ csr,
                                                unsigned int* __restrict__ out_u32) {
    int i = blockIdx.x * 4 + (threadIdx.x >> 6);
    if (i >= N_NODES) return;
    int l = threadIdx.x & 63;                        // u32 lane: channels 2l, 2l+1
    int k0 = offsets[i], k1 = offsets[i + 1];
    float a0 = 0.f, a1 = 0.f;
    int k = k0;
    for (; k + 3 < k1; k += 4) {
        int s0 = csr[k], s1 = csr[k + 1], s2 = csr[k + 2], s3 = csr[k + 3];
        unsigned int u0 = Abuf_u32[(size_t)s0 * 128 + 64 + l];
        unsigned int u1 = Abuf_u32[(size_t)s1 * 128 + 64 + l];
        unsigned int u2 = Abuf_u32[(size_t)s2 * 128 + 64 + l];
        unsigned int u3 = Abuf_u32[(size_t)s3 * 128 + 64 + l];
        a0 += bits2f(u0 << 16) + bits2f(u1 << 16) + bits2f(u2 << 16) + bits2f(u3 << 16);
        a1 += bits2f(u0 & 0xffff0000u) + bits2f(u1 & 0xffff0000u)
            + bits2f(u2 & 0xffff0000u) + bits2f(u3 & 0xffff0000u);
    }
    for (; k < k1; ++k) {
        unsigned int u = Abuf_u32[(size_t)csr[k] * 128 + 64 + l];
        a0 += bits2f(u << 16);
        a1 += bits2f(u & 0xffff0000u);
    }
    out_u32[(size_t)i * 128 + l] = ((unsigned int)f2bfbits(a1) << 16) | f2bfbits(a0);
}

// ---------------- MFMA GEMM ----------------
template<int K, int N, bool ELU, bool BIAS>
__global__ __launch_bounds__(256) void k_gemm(const __hip_bfloat16* __restrict__ A,
                                              const __hip_bfloat16* __restrict__ W,
                                              const float* __restrict__ bias,
                                              __hip_bfloat16* __restrict__ Out) {
    constexpr int NT = N / 16;
    int lane = threadIdx.x & 63, wave = threadIdx.x >> 6;
    int quad = lane >> 4, l16 = lane & 15;
    int rowA = blockIdx.x * 64 + wave * 16 + l16;
    int rowAc = rowA < N_NODES ? rowA : N_NODES - 1;
    const short* Ap  = (const short*)A + (size_t)rowAc * K + quad * 8;
    const short* Wp0 = (const short*)W + (size_t)l16 * K + quad * 8;
    f32x4 acc[NT];
    #pragma unroll
    for (int t = 0; t < NT; ++t) acc[t] = (f32x4){0.f, 0.f, 0.f, 0.f};
    #pragma unroll
    for (int k0 = 0; k0 < K; k0 += 32) {
        bf16x8 a = *(const bf16x8*)(Ap + k0);
        #pragma unroll
        for (int nt = 0; nt < NT; ++nt) {
            bf16x8 b = *(const bf16x8*)(Wp0 + (size_t)nt * 16 * K + k0);
            acc[nt] = __builtin_amdgcn_mfma_f32_16x16x32_bf16(a, b, acc[nt], 0, 0, 0);
        }
    }
    int mbase = blockIdx.x * 64 + wave * 16 + quad * 4;
    #pragma unroll
    for (int nt = 0; nt < NT; ++nt) {
        int col = nt * 16 + l16;
        float bv = BIAS ? bias[col] : 0.f;
        #pragma unroll
        for (int r = 0; r < 4; ++r) {
            int m = mbase + r;
            if (m < N_NODES) {
                float v = acc[nt][r] + bv;
                if (ELU) v = elu_f(v);
                Out[(size_t)m * N + col] = __float2bfloat16(v);
            }
        }
    }
}

// ---------------- alpha scalars ----------------
__global__ __launch_bounds__(256) void k_alpha1(const __hip_bfloat16* __restrict__ z1,
                                                const float* __restrict__ a_src,
                                                const float* __restrict__ a_dst,
                                                float* __restrict__ as1, float* __restrict__ ad1) {
    int i = blockIdx.x * 4 + (threadIdx.x >> 6);
    if (i >= N_NODES) return;
    int c = threadIdx.x & 63;
    float v = __bfloat162float(z1[(size_t)i * 64 + c]);
    float ps = v * a_src[c];
    float pd = v * a_dst[c];
    #pragma unroll
    for (int d = 4; d >= 1; d >>= 1) {
        ps += __shfl_down(ps, d, 8);
        pd += __shfl_down(pd, d, 8);
    }
    if ((c & 7) == 0) {
        as1[(size_t)i * 8 + (c >> 3)] = ps;
        ad1[(size_t)i * 8 + (c >> 3)] = pd;
    }
}

__global__ __launch_bounds__(256) void k_alpha2(const __hip_bfloat16* __restrict__ z2,
                                                const float* __restrict__ a_src,
                                                const float* __restrict__ a_dst,
                                                float* __restrict__ as2, float* __restrict__ ad2) {
    int i = blockIdx.x * 4 + (threadIdx.x >> 6);
    if (i >= N_NODES) return;
    int c = threadIdx.x & 63;
    float v = __bfloat162float(z2[(size_t)i * 64 + c]);
    float ps = v * a_src[c];
    float pd = v * a_dst[c];
    #pragma unroll
    for (int d = 32; d >= 1; d >>= 1) {
        ps += __shfl_down(ps, d, 64);
        pd += __shfl_down(pd, d, 64);
    }
    if (c == 0) { as2[i] = ps; ad2[i] = pd; }
}

// ---------------- edge weights (edge-parallel, coalesced writes) ----------------
// w1e[p][h] (bf16) = exp(lrelu(as1[src][h] + ad1[dst][h])), 8 heads packed in 16B
__global__ __launch_bounds__(256) void k_edgew1(const int* __restrict__ csr,
                                                const int* __restrict__ dpos,
                                                const float* __restrict__ as1,
                                                const float* __restrict__ ad1,
                                                ull* __restrict__ w1e) {
    int p = blockIdx.x * 256 + threadIdx.x;
    if (p >= N_EDGES) return;
    int s = csr[p], d = dpos[p];
    ull lo = 0, hi = 0;
    #pragma unroll
    for (int hh = 0; hh < 4; ++hh) {
        float w = __expf(lrelu_f(as1[(size_t)s * 8 + hh] + ad1[(size_t)d * 8 + hh]));
        lo |= (ull)f2bfbits(w) << (16 * hh);
    }
    #pragma unroll
    for (int hh = 0; hh < 4; ++hh) {
        float w = __expf(lrelu_f(as1[(size_t)s * 8 + 4 + hh] + ad1[(size_t)d * 8 + 4 + hh]));
        hi |= (ull)f2bfbits(w) << (16 * hh);
    }
    w1e[(size_t)p * 2]     = lo;
    w1e[(size_t)p * 2 + 1] = hi;
}

__global__ __launch_bounds__(256) void k_edgew2(const int* __restrict__ csr,
                                                const int* __restrict__ dpos,
                                                const float* __restrict__ as2,
                                                const float* __restrict__ ad2,
                                                float* __restrict__ w2e) {
    int p = blockIdx.x * 256 + threadIdx.x;
    if (p >= N_EDGES) return;
    w2e[p] = __expf(lrelu_f(as2[csr[p]] + ad2[dpos[p]]));
}

// ---------------- GAT1 attention: precomputed bf16 w, unroll 4 ----------------
__global__ __launch_bounds__(256) void k_gat1attn(const __hip_bfloat16* __restrict__ z1,
                                                  const float* __restrict__ as1,
                                                  const float* __restrict__ ad1,
                                                  const float* __restrict__ b1,
                                                  const int* __restrict__ offsets,
                                                  const int* __restrict__ csr,
                                                  const __hip_bfloat16* __restrict__ w1e,
                                                  __hip_bfloat16* __restrict__ h2) {
    int i = blockIdx.x * 4 + (threadIdx.x >> 6);
    if (i >= N_NODES) return;
    int t = threadIdx.x & 63;
    int hd = t >> 3;
    int k0 = offsets[i], k1 = offsets[i + 1];
    float ad = ad1[(size_t)i * 8 + hd];
    float e_self = __expf(lrelu_f(as1[(size_t)i * 8 + hd] + ad));
    float acc = e_self * __bfloat162float(z1[(size_t)i * 64 + t]);
    float den = e_self;
    int k = k0;
    for (; k + 3 < k1; k += 4) {
        int s0 = csr[k], s1 = csr[k + 1], s2 = csr[k + 2], s3 = csr[k + 3];
        float wa = __bfloat162float(w1e[(size_t)k * 8 + hd]);
        float wb = __bfloat162float(w1e[(size_t)(k + 1) * 8 + hd]);
        float wc = __bfloat162float(w1e[(size_t)(k + 2) * 8 + hd]);
        float wd = __bfloat162float(w1e[(size_t)(k + 3) * 8 + hd]);
        float v0 = __bfloat162float(z1[(size_t)s0 * 64 + t]);
        float v1 = __bfloat162float(z1[(size_t)s1 * 64 + t]);
        float v2 = __bfloat162float(z1[(size_t)s2 * 64 + t]);
        float v3 = __bfloat162float(z1[(size_t)s3 * 64 + t]);
        acc += wa * v0 + wb * v1 + wc * v2 + wd * v3;
        den += wa + wb + wc + wd;
    }
    for (; k < k1; ++k) {
        int s = csr[k];
        float w = __bfloat162float(w1e[(size_t)k * 8 + hd]);
        acc += w * __bfloat162float(z1[(size_t)s * 64 + t]);
        den += w;
    }
    h2[(size_t)i * 64 + t] = __float2bfloat16(elu_f(acc / den + b1[t]));
}

// ---------------- GAT2 attention + fused final dot, unroll 4 ----------------
// h3[i][t] = acc/den + b2[t]; contribution h3*Wr[t] wave-reduced into red bins.
__global__ __launch_bounds__(256) void k_gat2attn(const __hip_bfloat16* __restrict__ z2,
                                                  const float* __restrict__ as2,
                                                  const float* __restrict__ ad2,
                                                  const float* __restrict__ b2,
                                                  const int* __restrict__ offsets,
                                                  const int* __restrict__ csr,
                                                  const float* __restrict__ w2e,
                                                  const float* __restrict__ Wr,
                                                  float* __restrict__ red) {
    int i = blockIdx.x * 4 + (threadIdx.x >> 6);
    if (i >= N_NODES) return;
    int t = threadIdx.x & 63;
    int k0 = offsets[i], k1 = offsets[i + 1];
    float ad = ad2[i];
    float e_self = __expf(lrelu_f(as2[i] + ad));
    float acc = e_self * __bfloat162float(z2[(size_t)i * 64 + t]);
    float den = e_self;
    int k = k0;
    for (; k + 3 < k1; k += 4) {
        int s0 = csr[k], s1 = csr[k + 1], s2 = csr[k + 2], s3 = csr[k + 3];
        float wa = w2e[k], wb = w2e[k + 1], wc = w2e[k + 2], wd = w2e[k + 3];
        float v0 = __bfloat162float(z2[(size_t)s0 * 64 + t]);
        float v1 = __bfloat162float(z2[(size_t)s1 * 64 + t]);
        float v2 = __bfloat162float(z2[(size_t)s2 * 64 + t]);
        float v3 = __bfloat162float(z2[(size_t)s3 * 64 + t]);
        acc += wa * v0 + wb * v1 + wc * v2 + wd * v3;
        den += wa + wb + wc + wd;
    }
    for (; k < k1; ++k) {
        int s = csr[k];
        float w = w2e[k];
        acc += w * __bfloat162float(z2[(size_t)s * 64 + t]);
        den += w;
    }
    float c = (acc / den + b2[t]) * Wr[t];
    #pragma unroll
    for (int d = 32; d >= 1; d >>= 1) c += __shfl_xor(c, d, 64);
    if (t == 0) atomicAdd(&red[blockIdx.x & 255], c);
}

// ---------------- finalize: sum 256 bins, scale, add bias ----------------
__global__ void k_finalize(const float* __restrict__ red, const float* __restrict__ br,
                           float* __restrict__ out) {
    int t = threadIdx.x;    // 64 threads
    float s = red[t] + red[t + 64] + red[t + 128] + red[t + 192];
    #pragma unroll
    for (int d = 32; d >= 1; d >>= 1) s += __shfl_xor(s, d, 64);
    if (t == 0) out[0] = s * (1.0f / N_NODES) + br[0];
}

extern "C" void kernel_launch(void* const* d_in, const int* in_sizes, int n_in,
                              void* d_out, int out_size, void* d_ws, size_t ws_size,
                              hipStream_t stream) {
    const float* x      = (const float*)d_in[0];
    const int*   edges  = (const int*)d_in[1];
    const float* W_rel  = (const float*)d_in[2];
    const float* b_rel  = (const float*)d_in[3];
    const float* W_root = (const float*)d_in[4];
    const float* W1     = (const float*)d_in[5];
    const float* a1s    = (const float*)d_in[6];
    const float* a1d    = (const float*)d_in[7];
    const float* b1     = (const float*)d_in[8];
    const float* W2     = (const float*)d_in[9];
    const float* a2s    = (const float*)d_in[10];
    const float* a2d    = (const float*)d_in[11];
    const float* b2     = (const float*)d_in[12];
    const float* Wr     = (const float*)d_in[13];
    const float* br     = (const float*)d_in[14];
    float* out = (float*)d_out;

    const int* src = edges;
    const int* dst = edges + N_EDGES;

    char* ws = (char*)d_ws;
    size_t p = 0;
    auto alloc = [&](size_t bytes) -> void* {
        void* r = ws + p;
        p = (p + bytes + 255) & ~(size_t)255;
        return r;
    };
    int*   counts  = (int*)alloc((size_t)N_NODES * 4);
    int*   offsets = (int*)alloc((size_t)(N_NODES + 1) * 4);
    int*   cursor  = (int*)alloc((size_t)N_NODES * 4);
    int*   csr     = (int*)alloc((size_t)N_EDGES * 4);
    int*   dpos    = (int*)alloc((size_t)N_EDGES * 4);
    int*   part    = (int*)alloc((size_t)NB_SCAN * 4);
    __hip_bfloat16* Abuf = (__hip_bfloat16*)alloc((size_t)N_NODES * 256 * 2);  // [nbr | x]
    __hip_bfloat16* Wc   = (__hip_bfloat16*)alloc((size_t)128 * 256 * 2);
    __hip_bfloat16* W1b  = (__hip_bfloat16*)alloc((size_t)64 * 128 * 2);
    __hip_bfloat16* W2b  = (__hip_bfloat16*)alloc((size_t)64 * 64 * 2);
    __hip_bfloat16* h    = (__hip_bfloat16*)alloc((size_t)N_NODES * 128 * 2);
    __hip_bfloat16* z1b  = (__hip_bfloat16*)alloc((size_t)N_NODES * 64 * 2);
    float* as1 = (float*)alloc((size_t)N_NODES * 8 * 4);
    float* ad1 = (float*)alloc((size_t)N_NODES * 8 * 4);
    __hip_bfloat16* h2b  = (__hip_bfloat16*)alloc((size_t)N_NODES * 64 * 2);
    __hip_bfloat16* z2b  = (__hip_bfloat16*)alloc((size_t)N_NODES * 64 * 2);
    float* as2 = (float*)alloc((size_t)N_NODES * 4);
    float* ad2 = (float*)alloc((size_t)N_NODES * 4);
    __hip_bfloat16* w1e = (__hip_bfloat16*)alloc((size_t)N_EDGES * 8 * 2);   // 12.8 MB, fresh
    float* w2e = (float*)alloc((size_t)N_EDGES * 4);                         // 3.2 MB, fresh
    float* red = (float*)alloc(256 * 4);

    hipMemsetAsync(counts, 0, (size_t)N_NODES * 4, stream);
    hipMemsetAsync(red, 0, 256 * 4, stream);

    const int MB = (N_NODES + 63) / 64;     // 782
    const int NB4 = (N_NODES + 3) / 4;      // 12500
    const int EB = (N_EDGES + 255) / 256;   // 3125

    k_count  <<<EB, 256, 0, stream>>>(dst, counts);
    k_scanA  <<<NB_SCAN, 256, 0, stream>>>(counts, part);
    k_scanB  <<<1, 256, 0, stream>>>(part);
    k_scanC  <<<NB_SCAN, 256, 0, stream>>>(counts, part, offsets, cursor);
    k_scatter<<<EB, 256, 0, stream>>>(src, dst, cursor, csr, dpos);
    k_castx  <<<(N_NODES * 32 + 255) / 256, 256, 0, stream>>>(x, Abuf);
    k_castw  <<<(32768 + 8192 + 4096 + 255) / 256, 256, 0, stream>>>(W_rel, W_root, W1, W2, Wc, W1b, W2b);
    k_gather <<<NB4, 256, 0, stream>>>((const unsigned int*)Abuf, offsets, csr, (unsigned int*)Abuf);
    k_gemm<256, 128, true,  true ><<<MB, 256, 0, stream>>>(Abuf, Wc, b_rel, h);
    k_gemm<128, 64,  false, false><<<MB, 256, 0, stream>>>(h, W1b, nullptr, z1b);
    k_alpha1 <<<NB4, 256, 0, stream>>>(z1b, a1s, a1d, as1, ad1);
    k_edgew1 <<<EB, 256, 0, stream>>>(csr, dpos, as1, ad1, (ull*)w1e);
    k_gat1attn<<<NB4, 256, 0, stream>>>(z1b, as1, ad1, b1, offsets, csr, w1e, h2b);
    k_gemm<64, 64, false, false><<<MB, 256, 0, stream>>>(h2b, W2b, nullptr, z2b);
    k_alpha2 <<<NB4, 256, 0, stream>>>(z2b, a2s, a2d, as2, ad2);
    k_edgew2 <<<EB, 256, 0, stream>>>(csr, dpos, as2, ad2, w2e);
    k_gat2attn<<<NB4, 256, 0, stream>>>(z2b, as2, ad2, b2, offsets, csr, w2e, Wr, red);
    k_finalize<<<1, 64, 0, stream>>>(red, br, out);
}

// Round 7
// 380.369 us; speedup vs baseline: 2.7734x; 1.1641x over previous
//
#include <hip/hip_runtime.h>
#include <hip/hip_bf16.h>
#include <math.h>

#define N_NODES 50000
#define N_EDGES 800000
#define F_IN 128
#define NB_SCAN 196   // ceil(50000/256)

typedef __attribute__((ext_vector_type(8))) short bf16x8;
typedef __attribute__((ext_vector_type(4))) float f32x4;
typedef unsigned long long ull;

__device__ __forceinline__ float elu_f(float x)   { return x > 0.f ? x : expm1f(x); }
__device__ __forceinline__ float lrelu_f(float x) { return x > 0.f ? x : 0.2f * x; }
__device__ __forceinline__ int   clampN(int v)    { return v < 0 ? 0 : (v >= N_NODES ? N_NODES - 1 : v); }
__device__ __forceinline__ float bits2f(unsigned int u) { union { unsigned int u; float f; } x; x.u = u; return x.f; }
__device__ __forceinline__ float lo16(unsigned int u) { return bits2f(u << 16); }
__device__ __forceinline__ float hi16(unsigned int u) { return bits2f(u & 0xffff0000u); }
__device__ __forceinline__ unsigned short f2bfbits(float f) {
    __hip_bfloat16 b = __float2bfloat16(f);
    return __builtin_bit_cast(unsigned short, b);
}
__device__ __forceinline__ unsigned int pack2(float lo, float hi) {
    return ((unsigned int)f2bfbits(hi) << 16) | f2bfbits(lo);
}

// ---------------- CSR build ----------------
__global__ void k_count(const int* __restrict__ dst, int* __restrict__ counts) {
    int e = blockIdx.x * blockDim.x + threadIdx.x;
    if (e < N_EDGES) atomicAdd(&counts[clampN(dst[e])], 1);
}

__global__ __launch_bounds__(256) void k_scanA(const int* __restrict__ counts,
                                               int* __restrict__ part) {
    __shared__ int ws[4];
    int tid = threadIdx.x;
    int i = blockIdx.x * 256 + tid;
    int v = (i < N_NODES) ? counts[i] : 0;
    #pragma unroll
    for (int d = 32; d >= 1; d >>= 1) v += __shfl_down(v, d, 64);
    if ((tid & 63) == 0) ws[tid >> 6] = v;
    __syncthreads();
    if (tid == 0) part[blockIdx.x] = ws[0] + ws[1] + ws[2] + ws[3];
}

__global__ __launch_bounds__(256) void k_scanB(int* __restrict__ part) {
    __shared__ int wsum[4];
    __shared__ int wbase[4];
    int tid = threadIdx.x;
    int lane = tid & 63, wid = tid >> 6;
    int v = (tid < NB_SCAN) ? part[tid] : 0;
    int x = v;
    #pragma unroll
    for (int d = 1; d < 64; d <<= 1) {
        int t = __shfl_up(x, d, 64);
        if (lane >= d) x += t;
    }
    if (lane == 63) wsum[wid] = x;
    __syncthreads();
    if (tid == 0) {
        int b = 0;
        #pragma unroll
        for (int w = 0; w < 4; ++w) { wbase[w] = b; b += wsum[w]; }
    }
    __syncthreads();
    if (tid < NB_SCAN) part[tid] = wbase[wid] + x - v;
}

__global__ __launch_bounds__(256) void k_scanC(const int* __restrict__ counts,
                                               const int* __restrict__ part,
                                               int* __restrict__ offsets,
                                               int* __restrict__ cursor) {
    __shared__ int wsum[4];
    __shared__ int wbase[4];
    int tid = threadIdx.x;
    int lane = tid & 63, wid = tid >> 6;
    int i = blockIdx.x * 256 + tid;
    int v = (i < N_NODES) ? counts[i] : 0;
    int x = v;
    #pragma unroll
    for (int d = 1; d < 64; d <<= 1) {
        int t = __shfl_up(x, d, 64);
        if (lane >= d) x += t;
    }
    if (lane == 63) wsum[wid] = x;
    __syncthreads();
    if (tid == 0) {
        int b = part[blockIdx.x];
        #pragma unroll
        for (int w = 0; w < 4; ++w) { wbase[w] = b; b += wsum[w]; }
    }
    __syncthreads();
    if (i < N_NODES) {
        int excl = wbase[wid] + x - v;
        offsets[i] = excl;
        cursor[i]  = excl;
    }
    if (blockIdx.x == 0 && tid == 0) offsets[N_NODES] = N_EDGES;
}

__global__ void k_scatter(const int* __restrict__ src, const int* __restrict__ dst,
                          int* __restrict__ cursor, int* __restrict__ csr,
                          int* __restrict__ dpos) {
    int e = blockIdx.x * blockDim.x + threadIdx.x;
    if (e < N_EDGES) {
        int d = clampN(dst[e]);
        int pos = atomicAdd(&cursor[d], 1);
        csr[pos]  = clampN(src[e]);
        dpos[pos] = d;
    }
}

// ---------------- casts ----------------
__global__ void k_castx(const float* __restrict__ x, __hip_bfloat16* __restrict__ Abuf) {
    int id = blockIdx.x * 256 + threadIdx.x;        // covers 50000*32
    if (id >= N_NODES * 32) return;
    int i = id >> 5, c4 = (id & 31) * 4;
    float4 v = *(const float4*)&x[(size_t)i * 128 + c4];
    ull p = (ull)f2bfbits(v.x) | ((ull)f2bfbits(v.y) << 16)
          | ((ull)f2bfbits(v.z) << 32) | ((ull)f2bfbits(v.w) << 48);
    *(ull*)&Abuf[(size_t)i * 256 + 128 + c4] = p;
}

__global__ void k_castw(const float* __restrict__ W_rel, const float* __restrict__ W_root,
                        const float* __restrict__ W1, const float* __restrict__ W2,
                        __hip_bfloat16* __restrict__ Wc, __hip_bfloat16* __restrict__ W1b,
                        __hip_bfloat16* __restrict__ W2b) {
    int id = blockIdx.x * 256 + threadIdx.x;
    if (id < 32768) {
        int cc = id >> 8, k = id & 255;
        float v = (k < 128) ? W_rel[cc * 128 + k] : W_root[cc * 128 + (k - 128)];
        Wc[id] = __float2bfloat16(v);
    } else if (id < 32768 + 8192) {
        int j = id - 32768;
        W1b[j] = __float2bfloat16(W1[j]);
    } else if (id < 32768 + 8192 + 4096) {
        int j = id - 32768 - 8192;
        W2b[j] = __float2bfloat16(W2[j]);
    }
}

// ---------------- GraphConv gather: 2 nodes/wave, lane=32 covers row via 2 u32 ----------------
__global__ __launch_bounds__(256) void k_gather(const unsigned int* __restrict__ A,
                                                const int* __restrict__ offsets,
                                                const int* __restrict__ csr,
                                                unsigned int* __restrict__ out) {
    int i = blockIdx.x * 8 + (threadIdx.x >> 5);   // grid sized so i < N_NODES always
    int l = threadIdx.x & 31;
    int k0 = offsets[i], k1 = offsets[i + 1];
    float a0 = 0.f, a1 = 0.f, b0 = 0.f, b1v = 0.f;   // words l and l+32
    int k = k0;
    for (; k + 3 < k1; k += 4) {
        int s0 = csr[k], s1 = csr[k + 1], s2 = csr[k + 2], s3 = csr[k + 3];
        unsigned int ua0 = A[(size_t)s0 * 128 + 64 + l];
        unsigned int va0 = A[(size_t)s0 * 128 + 96 + l];
        unsigned int ua1 = A[(size_t)s1 * 128 + 64 + l];
        unsigned int va1 = A[(size_t)s1 * 128 + 96 + l];
        unsigned int ua2 = A[(size_t)s2 * 128 + 64 + l];
        unsigned int va2 = A[(size_t)s2 * 128 + 96 + l];
        unsigned int ua3 = A[(size_t)s3 * 128 + 64 + l];
        unsigned int va3 = A[(size_t)s3 * 128 + 96 + l];
        a0  += lo16(ua0) + lo16(ua1) + lo16(ua2) + lo16(ua3);
        a1  += hi16(ua0) + hi16(ua1) + hi16(ua2) + hi16(ua3);
        b0  += lo16(va0) + lo16(va1) + lo16(va2) + lo16(va3);
        b1v += hi16(va0) + hi16(va1) + hi16(va2) + hi16(va3);
    }
    for (; k < k1; ++k) {
        int s = csr[k];
        unsigned int ua = A[(size_t)s * 128 + 64 + l];
        unsigned int va = A[(size_t)s * 128 + 96 + l];
        a0 += lo16(ua); a1 += hi16(ua);
        b0 += lo16(va); b1v += hi16(va);
    }
    out[(size_t)i * 128 + l]      = pack2(a0, a1);
    out[(size_t)i * 128 + 32 + l] = pack2(b0, b1v);
}

// ---------------- MFMA GEMM ----------------
template<int K, int N, bool ELU, bool BIAS>
__global__ __launch_bounds__(256) void k_gemm(const __hip_bfloat16* __restrict__ A,
                                              const __hip_bfloat16* __restrict__ W,
                                              const float* __restrict__ bias,
                                              __hip_bfloat16* __restrict__ Out) {
    constexpr int NT = N / 16;
    int lane = threadIdx.x & 63, wave = threadIdx.x >> 6;
    int quad = lane >> 4, l16 = lane & 15;
    int rowA = blockIdx.x * 64 + wave * 16 + l16;
    int rowAc = rowA < N_NODES ? rowA : N_NODES - 1;
    const short* Ap  = (const short*)A + (size_t)rowAc * K + quad * 8;
    const short* Wp0 = (const short*)W + (size_t)l16 * K + quad * 8;
    f32x4 acc[NT];
    #pragma unroll
    for (int t = 0; t < NT; ++t) acc[t] = (f32x4){0.f, 0.f, 0.f, 0.f};
    #pragma unroll
    for (int k0 = 0; k0 < K; k0 += 32) {
        bf16x8 a = *(const bf16x8*)(Ap + k0);
        #pragma unroll
        for (int nt = 0; nt < NT; ++nt) {
            bf16x8 b = *(const bf16x8*)(Wp0 + (size_t)nt * 16 * K + k0);
            acc[nt] = __builtin_amdgcn_mfma_f32_16x16x32_bf16(a, b, acc[nt], 0, 0, 0);
        }
    }
    int mbase = blockIdx.x * 64 + wave * 16 + quad * 4;
    #pragma unroll
    for (int nt = 0; nt < NT; ++nt) {
        int col = nt * 16 + l16;
        float bv = BIAS ? bias[col] : 0.f;
        #pragma unroll
        for (int r = 0; r < 4; ++r) {
            int m = mbase + r;
            if (m < N_NODES) {
                float v = acc[nt][r] + bv;
                if (ELU) v = elu_f(v);
                Out[(size_t)m * N + col] = __float2bfloat16(v);
            }
        }
    }
}

// ---------------- alpha scalars ----------------
__global__ __launch_bounds__(256) void k_alpha1(const __hip_bfloat16* __restrict__ z1,
                                                const float* __restrict__ a_src,
                                                const float* __restrict__ a_dst,
                                                float* __restrict__ as1, float* __restrict__ ad1) {
    int i = blockIdx.x * 4 + (threadIdx.x >> 6);
    if (i >= N_NODES) return;
    int c = threadIdx.x & 63;
    float v = __bfloat162float(z1[(size_t)i * 64 + c]);
    float ps = v * a_src[c];
    float pd = v * a_dst[c];
    #pragma unroll
    for (int d = 4; d >= 1; d >>= 1) {
        ps += __shfl_down(ps, d, 8);
        pd += __shfl_down(pd, d, 8);
    }
    if ((c & 7) == 0) {
        as1[(size_t)i * 8 + (c >> 3)] = ps;
        ad1[(size_t)i * 8 + (c >> 3)] = pd;
    }
}

__global__ __launch_bounds__(256) void k_alpha2(const __hip_bfloat16* __restrict__ z2,
                                                const float* __restrict__ a_src,
                                                const float* __restrict__ a_dst,
                                                float* __restrict__ as2, float* __restrict__ ad2) {
    int i = blockIdx.x * 4 + (threadIdx.x >> 6);
    if (i >= N_NODES) return;
    int c = threadIdx.x & 63;
    float v = __bfloat162float(z2[(size_t)i * 64 + c]);
    float ps = v * a_src[c];
    float pd = v * a_dst[c];
    #pragma unroll
    for (int d = 32; d >= 1; d >>= 1) {
        ps += __shfl_down(ps, d, 64);
        pd += __shfl_down(pd, d, 64);
    }
    if (c == 0) { as2[i] = ps; ad2[i] = pd; }
}

// ---------------- GAT1 edge weights (bf16, 8 heads / edge) ----------------
__global__ __launch_bounds__(256) void k_edgew1(const int* __restrict__ csr,
                                                const int* __restrict__ dpos,
                                                const float* __restrict__ as1,
                                                const float* __restrict__ ad1,
                                                ull* __restrict__ w1e) {
    int p = blockIdx.x * 256 + threadIdx.x;
    if (p >= N_EDGES) return;
    int s = csr[p], d = dpos[p];
    ull lo = 0, hi = 0;
    #pragma unroll
    for (int hh = 0; hh < 4; ++hh) {
        float w = __expf(lrelu_f(as1[(size_t)s * 8 + hh] + ad1[(size_t)d * 8 + hh]));
        lo |= (ull)f2bfbits(w) << (16 * hh);
    }
    #pragma unroll
    for (int hh = 0; hh < 4; ++hh) {
        float w = __expf(lrelu_f(as1[(size_t)s * 8 + 4 + hh] + ad1[(size_t)d * 8 + 4 + hh]));
        hi |= (ull)f2bfbits(w) << (16 * hh);
    }
    w1e[(size_t)p * 2]     = lo;
    w1e[(size_t)p * 2 + 1] = hi;
}

// ---------------- GAT1 attention: 2 nodes/wave, precomputed bf16 w ----------------
__global__ __launch_bounds__(256) void k_gat1attn(const unsigned int* __restrict__ z1u,
                                                  const float* __restrict__ as1,
                                                  const float* __restrict__ ad1,
                                                  const float* __restrict__ b1,
                                                  const int* __restrict__ offsets,
                                                  const int* __restrict__ csr,
                                                  const __hip_bfloat16* __restrict__ w1e,
                                                  unsigned int* __restrict__ h2u) {
    int i = blockIdx.x * 8 + (threadIdx.x >> 5);
    int l = threadIdx.x & 31;      // u32 word: channels 2l, 2l+1 (same head l>>2)
    int hd = l >> 2;
    int k0 = offsets[i], k1 = offsets[i + 1];
    float ad = ad1[(size_t)i * 8 + hd];
    float e_self = __expf(lrelu_f(as1[(size_t)i * 8 + hd] + ad));
    unsigned int uz = z1u[(size_t)i * 32 + l];
    float acc0 = e_self * lo16(uz);
    float acc1 = e_self * hi16(uz);
    float den = e_self;
    int k = k0;
    for (; k + 3 < k1; k += 4) {
        int s0 = csr[k], s1 = csr[k + 1], s2 = csr[k + 2], s3 = csr[k + 3];
        float wa = __bfloat162float(w1e[(size_t)k * 8 + hd]);
        float wb = __bfloat162float(w1e[(size_t)(k + 1) * 8 + hd]);
        float wc = __bfloat162float(w1e[(size_t)(k + 2) * 8 + hd]);
        float wd = __bfloat162float(w1e[(size_t)(k + 3) * 8 + hd]);
        unsigned int u0 = z1u[(size_t)s0 * 32 + l];
        unsigned int u1 = z1u[(size_t)s1 * 32 + l];
        unsigned int u2 = z1u[(size_t)s2 * 32 + l];
        unsigned int u3 = z1u[(size_t)s3 * 32 + l];
        acc0 += wa * lo16(u0) + wb * lo16(u1) + wc * lo16(u2) + wd * lo16(u3);
        acc1 += wa * hi16(u0) + wb * hi16(u1) + wc * hi16(u2) + wd * hi16(u3);
        den += wa + wb + wc + wd;
    }
    for (; k < k1; ++k) {
        int s = csr[k];
        float w = __bfloat162float(w1e[(size_t)k * 8 + hd]);
        unsigned int u = z1u[(size_t)s * 32 + l];
        acc0 += w * lo16(u);
        acc1 += w * hi16(u);
        den += w;
    }
    float inv = 1.f / den;
    float r0 = elu_f(acc0 * inv + b1[2 * l]);
    float r1 = elu_f(acc1 * inv + b1[2 * l + 1]);
    h2u[(size_t)i * 32 + l] = pack2(r0, r1);
}

// ---------------- GAT2 attention: 2 nodes/wave, inline exp, fused final dot ----------------
__global__ __launch_bounds__(256) void k_gat2attn(const unsigned int* __restrict__ z2u,
                                                  const float* __restrict__ as2,
                                                  const float* __restrict__ ad2,
                                                  const float* __restrict__ b2,
                                                  const int* __restrict__ offsets,
                                                  const int* __restrict__ csr,
                                                  const float* __restrict__ Wr,
                                                  float* __restrict__ red) {
    int i = blockIdx.x * 8 + (threadIdx.x >> 5);
    int l = threadIdx.x & 31;
    int k0 = offsets[i], k1 = offsets[i + 1];
    float ad = ad2[i];
    float e_self = __expf(lrelu_f(as2[i] + ad));
    unsigned int uz = z2u[(size_t)i * 32 + l];
    float acc0 = e_self * lo16(uz);
    float acc1 = e_self * hi16(uz);
    float den = e_self;
    int k = k0;
    for (; k + 3 < k1; k += 4) {
        int s0 = csr[k], s1 = csr[k + 1], s2 = csr[k + 2], s3 = csr[k + 3];
        float ea = __expf(lrelu_f(as2[s0] + ad));
        float eb = __expf(lrelu_f(as2[s1] + ad));
        float ec = __expf(lrelu_f(as2[s2] + ad));
        float ed = __expf(lrelu_f(as2[s3] + ad));
        unsigned int u0 = z2u[(size_t)s0 * 32 + l];
        unsigned int u1 = z2u[(size_t)s1 * 32 + l];
        unsigned int u2 = z2u[(size_t)s2 * 32 + l];
        unsigned int u3 = z2u[(size_t)s3 * 32 + l];
        acc0 += ea * lo16(u0) + eb * lo16(u1) + ec * lo16(u2) + ed * lo16(u3);
        acc1 += ea * hi16(u0) + eb * hi16(u1) + ec * hi16(u2) + ed * hi16(u3);
        den += ea + eb + ec + ed;
    }
    for (; k < k1; ++k) {
        int s = csr[k];
        float e = __expf(lrelu_f(as2[s] + ad));
        unsigned int u = z2u[(size_t)s * 32 + l];
        acc0 += e * lo16(u);
        acc1 += e * hi16(u);
        den += e;
    }
    float inv = 1.f / den;
    float c = (acc0 * inv + b2[2 * l]) * Wr[2 * l]
            + (acc1 * inv + b2[2 * l + 1]) * Wr[2 * l + 1];
    #pragma unroll
    for (int d = 16; d >= 1; d >>= 1) c += __shfl_xor(c, d, 64);   // within 32-lane half
    if (l == 0) atomicAdd(&red[blockIdx.x & 255], c);
}

// ---------------- finalize: sum 256 bins, scale, add bias ----------------
__global__ void k_finalize(const float* __restrict__ red, const float* __restrict__ br,
                           float* __restrict__ out) {
    int t = threadIdx.x;    // 64 threads
    float s = red[t] + red[t + 64] + red[t + 128] + red[t + 192];
    #pragma unroll
    for (int d = 32; d >= 1; d >>= 1) s += __shfl_xor(s, d, 64);
    if (t == 0) out[0] = s * (1.0f / N_NODES) + br[0];
}

extern "C" void kernel_launch(void* const* d_in, const int* in_sizes, int n_in,
                              void* d_out, int out_size, void* d_ws, size_t ws_size,
                              hipStream_t stream) {
    const float* x      = (const float*)d_in[0];
    const int*   edges  = (const int*)d_in[1];
    const float* W_rel  = (const float*)d_in[2];
    const float* b_rel  = (const float*)d_in[3];
    const float* W_root = (const float*)d_in[4];
    const float* W1     = (const float*)d_in[5];
    const float* a1s    = (const float*)d_in[6];
    const float* a1d    = (const float*)d_in[7];
    const float* b1     = (const float*)d_in[8];
    const float* W2     = (const float*)d_in[9];
    const float* a2s    = (const float*)d_in[10];
    const float* a2d    = (const float*)d_in[11];
    const float* b2     = (const float*)d_in[12];
    const float* Wr     = (const float*)d_in[13];
    const float* br     = (const float*)d_in[14];
    float* out = (float*)d_out;

    const int* src = edges;
    const int* dst = edges + N_EDGES;

    char* ws = (char*)d_ws;
    size_t p = 0;
    auto alloc = [&](size_t bytes) -> void* {
        void* r = ws + p;
        p = (p + bytes + 255) & ~(size_t)255;
        return r;
    };
    int*   counts  = (int*)alloc((size_t)N_NODES * 4);
    int*   offsets = (int*)alloc((size_t)(N_NODES + 1) * 4);
    int*   cursor  = (int*)alloc((size_t)N_NODES * 4);
    int*   csr     = (int*)alloc((size_t)N_EDGES * 4);
    int*   dpos    = (int*)alloc((size_t)N_EDGES * 4);
    int*   part    = (int*)alloc((size_t)NB_SCAN * 4);
    __hip_bfloat16* Abuf = (__hip_bfloat16*)alloc((size_t)N_NODES * 256 * 2);  // [nbr | x]
    __hip_bfloat16* Wc   = (__hip_bfloat16*)alloc((size_t)128 * 256 * 2);
    __hip_bfloat16* W1b  = (__hip_bfloat16*)alloc((size_t)64 * 128 * 2);
    __hip_bfloat16* W2b  = (__hip_bfloat16*)alloc((size_t)64 * 64 * 2);
    __hip_bfloat16* h    = (__hip_bfloat16*)alloc((size_t)N_NODES * 128 * 2);
    __hip_bfloat16* z1b  = (__hip_bfloat16*)alloc((size_t)N_NODES * 64 * 2);
    float* as1 = (float*)alloc((size_t)N_NODES * 8 * 4);
    float* ad1 = (float*)alloc((size_t)N_NODES * 8 * 4);
    __hip_bfloat16* h2b  = (__hip_bfloat16*)alloc((size_t)N_NODES * 64 * 2);
    __hip_bfloat16* z2b  = (__hip_bfloat16*)alloc((size_t)N_NODES * 64 * 2);
    float* as2 = (float*)alloc((size_t)N_NODES * 4);
    float* ad2 = (float*)alloc((size_t)N_NODES * 4);
    __hip_bfloat16* w1e = (__hip_bfloat16*)alloc((size_t)N_EDGES * 8 * 2);   // 12.8 MB
    float* red = (float*)alloc(256 * 4);

    hipMemsetAsync(counts, 0, (size_t)N_NODES * 4, stream);
    hipMemsetAsync(red, 0, 256 * 4, stream);

    const int MB  = (N_NODES + 63) / 64;    // 782
    const int NB4 = (N_NODES + 3) / 4;      // 12500
    const int NB8 = N_NODES / 8;            // 6250 (50000 % 8 == 0)
    const int EB  = (N_EDGES + 255) / 256;  // 3125

    k_count  <<<EB, 256, 0, stream>>>(dst, counts);
    k_scanA  <<<NB_SCAN, 256, 0, stream>>>(counts, part);
    k_scanB  <<<1, 256, 0, stream>>>(part);
    k_scanC  <<<NB_SCAN, 256, 0, stream>>>(counts, part, offsets, cursor);
    k_scatter<<<EB, 256, 0, stream>>>(src, dst, cursor, csr, dpos);
    k_castx  <<<(N_NODES * 32 + 255) / 256, 256, 0, stream>>>(x, Abuf);
    k_castw  <<<(32768 + 8192 + 4096 + 255) / 256, 256, 0, stream>>>(W_rel, W_root, W1, W2, Wc, W1b, W2b);
    k_gather <<<NB8, 256, 0, stream>>>((const unsigned int*)Abuf, offsets, csr, (unsigned int*)Abuf);
    k_gemm<256, 128, true,  true ><<<MB, 256, 0, stream>>>(Abuf, Wc, b_rel, h);
    k_gemm<128, 64,  false, false><<<MB, 256, 0, stream>>>(h, W1b, nullptr, z1b);
    k_alpha1 <<<NB4, 256, 0, stream>>>(z1b, a1s, a1d, as1, ad1);
    k_edgew1 <<<EB, 256, 0, stream>>>(csr, dpos, as1, ad1, (ull*)w1e);
    k_gat1attn<<<NB8, 256, 0, stream>>>((const unsigned int*)z1b, as1, ad1, b1, offsets, csr, w1e, (unsigned int*)h2b);
    k_gemm<64, 64, false, false><<<MB, 256, 0, stream>>>(h2b, W2b, nullptr, z2b);
    k_alpha2 <<<NB4, 256, 0, stream>>>(z2b, a2s, a2d, as2, ad2);
    k_gat2attn<<<NB8, 256, 0, stream>>>((const unsigned int*)z2b, as2, ad2, b2, offsets, csr, Wr, red);
    k_finalize<<<1, 64, 0, stream>>>(red, br, out);
}